// Round 9
// baseline (1212.258 us; speedup 1.0000x reference)
//
#include <hip/hip_runtime.h>

// Problem constants: N=50000, E=800000, IN=128, HID=64, OUT=40
#define HID 64
#define JK_DIM 192
#define OUT_DIM 40
#define A_PITCH 68     // gemm_tile A-tile pitch: 16B aligned, max 2-way bank alias
#define W_PITCH 196    // final_gemm LDS pitch for Wt rows
#define FG_PITCH 44    // final_gemm epilogue staging pitch
#define BSH 5          // log2(nodes per bucket)
#define BNODES 32      // nodes per bucket -> 8 KB LDS accumulator

// ---------------------------------------------------------------------------
// Register-tiled GEMM: out[64x64 tile] = h[64 x K] @ W[K x 64].
// Block = 256 threads -> 16 row-groups x 16 col-groups, thread = 4x4 tile.
// ---------------------------------------------------------------------------
template <int K>
__global__ __launch_bounds__(256) void gemm_tile(const float* __restrict__ h, int inStride,
                                                 const float* __restrict__ W,
                                                 float* __restrict__ out, int outStride,
                                                 int n) {
    __shared__ float As[64 * A_PITCH];
    __shared__ float Ws[64 * HID];
    int tid = threadIdx.x;
    int rg = tid >> 4;
    int cgrp = tid & 15;
    int c0 = cgrp * 4;
    int row0 = blockIdx.x * 64;
    if (row0 >= n) return;

    float acc[4][4] = {{0.f}};

    for (int kb = 0; kb < K; kb += 64) {
        for (int i = tid; i < 64 * 16; i += 256) {
            int r = i >> 4;
            int c4 = (i & 15) * 4;
            int grow = row0 + r;
            if (grow >= n) grow = n - 1;
            float4 v = *(const float4*)(h + (long)grow * inStride + kb + c4);
            *(float4*)(As + r * A_PITCH + c4) = v;
        }
        for (int i = tid; i < 64 * 16; i += 256) {
            int k = i >> 4;
            int c4 = (i & 15) * 4;
            *(float4*)(Ws + k * HID + c4) = *(const float4*)(W + (long)(kb + k) * HID + c4);
        }
        __syncthreads();
#pragma unroll 4
        for (int k = 0; k < 64; k += 4) {
            float4 w0 = *(const float4*)(Ws + (k + 0) * HID + c0);
            float4 w1 = *(const float4*)(Ws + (k + 1) * HID + c0);
            float4 w2 = *(const float4*)(Ws + (k + 2) * HID + c0);
            float4 w3 = *(const float4*)(Ws + (k + 3) * HID + c0);
#pragma unroll
            for (int r = 0; r < 4; ++r) {
                float4 a = *(const float4*)(As + (rg * 4 + r) * A_PITCH + k);
                acc[r][0] += a.x * w0.x + a.y * w1.x + a.z * w2.x + a.w * w3.x;
                acc[r][1] += a.x * w0.y + a.y * w1.y + a.z * w2.y + a.w * w3.y;
                acc[r][2] += a.x * w0.z + a.y * w1.z + a.z * w2.z + a.w * w3.z;
                acc[r][3] += a.x * w0.w + a.y * w1.w + a.z * w2.w + a.w * w3.w;
            }
        }
        __syncthreads();
    }
#pragma unroll
    for (int r = 0; r < 4; ++r) {
        int grow = row0 + rg * 4 + r;
        if (grow < n) {
            float4 o = make_float4(acc[r][0], acc[r][1], acc[r][2], acc[r][3]);
            *(float4*)(out + (long)grow * outStride + c0) = o;
        }
    }
}

// ---------------------------------------------------------------------------
// Bucket histogram: LDS-privatized counts of dst>>BSH, flushed once per block.
// ---------------------------------------------------------------------------
__global__ __launch_bounds__(256) void hist_bucket(const int* __restrict__ dst,
                                                   int* __restrict__ bcnt,
                                                   int E, int nb) {
    __shared__ int h[1600];
    for (int i = threadIdx.x; i < nb; i += 256) h[i] = 0;
    __syncthreads();
    for (int e = blockIdx.x * 256 + threadIdx.x; e < E; e += gridDim.x * 256)
        atomicAdd(&h[dst[e] >> BSH], 1);
    __syncthreads();
    for (int i = threadIdx.x; i < nb; i += 256) {
        int v = h[i];
        if (v) atomicAdd(&bcnt[i], v);
    }
}

// ---------------------------------------------------------------------------
// Exclusive scan over nb elements (nb <= 256*256): 3 passes.
// ---------------------------------------------------------------------------
__global__ __launch_bounds__(256) void scan_a(const int* __restrict__ deg,
                                              int* __restrict__ off,
                                              int* __restrict__ bsum, int n) {
    __shared__ int tmp[256];
    int i = blockIdx.x * 256 + threadIdx.x;
    int v = (i < n) ? deg[i] : 0;
    tmp[threadIdx.x] = v;
    __syncthreads();
    for (int d = 1; d < 256; d <<= 1) {
        int t = (threadIdx.x >= d) ? tmp[threadIdx.x - d] : 0;
        __syncthreads();
        tmp[threadIdx.x] += t;
        __syncthreads();
    }
    if (i < n) off[i] = tmp[threadIdx.x] - v;
    if (threadIdx.x == 255) bsum[blockIdx.x] = tmp[255];
}

__global__ __launch_bounds__(256) void scan_b(int* __restrict__ bsum, int nblk) {
    __shared__ int tmp[256];
    int v = (threadIdx.x < nblk) ? bsum[threadIdx.x] : 0;
    tmp[threadIdx.x] = v;
    __syncthreads();
    for (int d = 1; d < 256; d <<= 1) {
        int t = (threadIdx.x >= d) ? tmp[threadIdx.x - d] : 0;
        __syncthreads();
        tmp[threadIdx.x] += t;
        __syncthreads();
    }
    if (threadIdx.x < nblk) bsum[threadIdx.x] = tmp[threadIdx.x] - v;
}

__global__ __launch_bounds__(256) void scan_c(int* __restrict__ off,
                                              const int* __restrict__ bsum,
                                              int* __restrict__ pos, int n) {
    int i = blockIdx.x * 256 + threadIdx.x;
    if (i >= n) return;
    int o = off[i] + bsum[blockIdx.x];
    off[i] = o;
    pos[i] = o;
}

// ---------------------------------------------------------------------------
// Bucket scatter: record = (src | dstLow<<20, weight) into the dst bucket's
// region. 1563 concurrent cursors -> stores cluster into advancing windows
// -> L2 write-coalesced (unlike the 50k-cursor exact sort).
// ---------------------------------------------------------------------------
__global__ __launch_bounds__(256) void fill_bucket(const int* __restrict__ src,
                                                   const int* __restrict__ dst,
                                                   const float* __restrict__ ew,
                                                   int* __restrict__ bcur,
                                                   int2* __restrict__ etmp, int E) {
    int e = blockIdx.x * 256 + threadIdx.x;
    if (e >= E) return;
    int d = dst[e];
    int p = atomicAdd(&bcur[d >> BSH], 1);
    int2 v;
    v.x = src[e] | ((d & (BNODES - 1)) << 20);
    v.y = __float_as_int(ew[e]);
    etmp[p] = v;
}

// ---------------------------------------------------------------------------
// Bucket aggregate + bias + ReLU. One block per bucket of 32 nodes; 8 KB
// LDS f32 accumulator. Records are read sequentially; each 16-lane group
// keeps 4 float4 gathers in flight (16/wave); products land in LDS via
// native ds_add_f32 (bank layout d*64+c -> only the free 2-way alias).
// Epilogue: bias+ReLU, one float4-coalesced row write per node.
// ---------------------------------------------------------------------------
__global__ __launch_bounds__(256) void agg_bucket(const float* __restrict__ lin,
                                                  const int2* __restrict__ etmp,
                                                  const int* __restrict__ boff,
                                                  const float* __restrict__ bias,
                                                  float* __restrict__ hout,
                                                  int n, int E, int nb) {
    __shared__ float acc[BNODES * HID];  // 8192 B
    int tid = threadIdx.x;
    int b = blockIdx.x;
    for (int i = tid; i < BNODES * HID / 4; i += 256)
        *(float4*)(acc + i * 4) = make_float4(0.f, 0.f, 0.f, 0.f);
    int start = boff[b];
    int end = (b + 1 < nb) ? boff[b + 1] : E;
    __syncthreads();

    int wave = tid >> 6;
    int g = (tid >> 4) & 3;
    int cl = tid & 15;
    int c4 = cl * 4;
    for (int base = start + wave * 16 + g * 4; base < end; base += 64) {
        int2 r0 = (base + 0 < end) ? etmp[base + 0] : make_int2(0, 0);
        int2 r1 = (base + 1 < end) ? etmp[base + 1] : make_int2(0, 0);
        int2 r2 = (base + 2 < end) ? etmp[base + 2] : make_int2(0, 0);
        int2 r3 = (base + 3 < end) ? etmp[base + 3] : make_int2(0, 0);
        float4 v0 = *(const float4*)(lin + (long)(r0.x & 0xFFFFF) * HID + c4);
        float4 v1 = *(const float4*)(lin + (long)(r1.x & 0xFFFFF) * HID + c4);
        float4 v2 = *(const float4*)(lin + (long)(r2.x & 0xFFFFF) * HID + c4);
        float4 v3 = *(const float4*)(lin + (long)(r3.x & 0xFFFFF) * HID + c4);
        float w0 = __int_as_float(r0.y);
        float w1 = __int_as_float(r1.y);
        float w2 = __int_as_float(r2.y);
        float w3 = __int_as_float(r3.y);
        float* a0 = acc + (r0.x >> 20) * HID + c4;
        float* a1 = acc + (r1.x >> 20) * HID + c4;
        float* a2 = acc + (r2.x >> 20) * HID + c4;
        float* a3 = acc + (r3.x >> 20) * HID + c4;
        atomicAdd(a0 + 0, v0.x * w0); atomicAdd(a0 + 1, v0.y * w0);
        atomicAdd(a0 + 2, v0.z * w0); atomicAdd(a0 + 3, v0.w * w0);
        atomicAdd(a1 + 0, v1.x * w1); atomicAdd(a1 + 1, v1.y * w1);
        atomicAdd(a1 + 2, v1.z * w1); atomicAdd(a1 + 3, v1.w * w1);
        atomicAdd(a2 + 0, v2.x * w2); atomicAdd(a2 + 1, v2.y * w2);
        atomicAdd(a2 + 2, v2.z * w2); atomicAdd(a2 + 3, v2.w * w2);
        atomicAdd(a3 + 0, v3.x * w3); atomicAdd(a3 + 1, v3.y * w3);
        atomicAdd(a3 + 2, v3.z * w3); atomicAdd(a3 + 3, v3.w * w3);
    }
    __syncthreads();

    int nodeBase = b << BSH;
    for (int i = tid; i < BNODES * 16; i += 256) {
        int row = i >> 4;
        int cc = (i & 15) * 4;
        int node = nodeBase + row;
        if (node < n) {
            float4 a = *(const float4*)(acc + row * HID + cc);
            float4 bb = *(const float4*)(bias + cc);
            float4 o;
            o.x = fmaxf(a.x + bb.x, 0.f);
            o.y = fmaxf(a.y + bb.y, 0.f);
            o.z = fmaxf(a.z + bb.z, 0.f);
            o.w = fmaxf(a.w + bb.w, 0.f);
            *(float4*)(hout + (long)node * JK_DIM + cc) = o;
        }
    }
}

// ---------------------------------------------------------------------------
// Transpose Wlin[192,40] -> Wt[40,192] (runs once, stays L2-hot).
// ---------------------------------------------------------------------------
__global__ __launch_bounds__(256) void transpose_w(const float* __restrict__ W,
                                                   float* __restrict__ Wt) {
    int i = blockIdx.x * 256 + threadIdx.x;
    if (i < JK_DIM * OUT_DIM) {
        int k = i / OUT_DIM;
        int c = i - k * OUT_DIM;
        Wt[c * JK_DIM + k] = W[i];
    }
}

// ---------------------------------------------------------------------------
// Final: out[n,40] = hcat[n,192] @ Wlin[192,40] + blin.
// 64-row tile per 256-thread block; thread = 2 rows x 5 cols; Wt in LDS at
// pitch 196; pool reused as epilogue staging for coalesced float4 stores.
// ---------------------------------------------------------------------------
__global__ __launch_bounds__(256) void final_gemm(const float* __restrict__ hcat,
                                                  const float* __restrict__ Wt,
                                                  const float* __restrict__ b,
                                                  float* __restrict__ out, int n) {
    __shared__ float pool[OUT_DIM * W_PITCH];  // 31360 B
    int tid = threadIdx.x;
    for (int i = tid; i < OUT_DIM * 48; i += 256) {
        int c = i / 48;
        int q = (i - c * 48) * 4;
        *(float4*)(pool + c * W_PITCH + q) = *(const float4*)(Wt + (long)c * JK_DIM + q);
    }
    __syncthreads();

    int rg = tid >> 3;
    int cg = tid & 7;
    int c0 = cg * 5;
    int row0 = blockIdx.x * 64;
    int r0 = row0 + rg * 2;
    int ra = r0 < n ? r0 : n - 1;
    int rb = r0 + 1 < n ? r0 + 1 : n - 1;
    const float* ha = hcat + (long)ra * JK_DIM;
    const float* hb = hcat + (long)rb * JK_DIM;

    float acc[2][5];
#pragma unroll
    for (int r = 0; r < 2; ++r)
#pragma unroll
        for (int i = 0; i < 5; ++i) acc[r][i] = 0.f;

#pragma unroll 4
    for (int k = 0; k < JK_DIM; k += 4) {
        float4 va = *(const float4*)(ha + k);
        float4 vb = *(const float4*)(hb + k);
        float4 w0 = *(const float4*)(pool + (c0 + 0) * W_PITCH + k);
        float4 w1 = *(const float4*)(pool + (c0 + 1) * W_PITCH + k);
        float4 w2 = *(const float4*)(pool + (c0 + 2) * W_PITCH + k);
        float4 w3 = *(const float4*)(pool + (c0 + 3) * W_PITCH + k);
        float4 w4 = *(const float4*)(pool + (c0 + 4) * W_PITCH + k);
        acc[0][0] += va.x * w0.x + va.y * w0.y + va.z * w0.z + va.w * w0.w;
        acc[0][1] += va.x * w1.x + va.y * w1.y + va.z * w1.z + va.w * w1.w;
        acc[0][2] += va.x * w2.x + va.y * w2.y + va.z * w2.z + va.w * w2.w;
        acc[0][3] += va.x * w3.x + va.y * w3.y + va.z * w3.z + va.w * w3.w;
        acc[0][4] += va.x * w4.x + va.y * w4.y + va.z * w4.z + va.w * w4.w;
        acc[1][0] += vb.x * w0.x + vb.y * w0.y + vb.z * w0.z + vb.w * w0.w;
        acc[1][1] += vb.x * w1.x + vb.y * w1.y + vb.z * w1.z + vb.w * w1.w;
        acc[1][2] += vb.x * w2.x + vb.y * w2.y + vb.z * w2.z + vb.w * w2.w;
        acc[1][3] += vb.x * w3.x + vb.y * w3.y + vb.z * w3.z + vb.w * w3.w;
        acc[1][4] += vb.x * w4.x + vb.y * w4.y + vb.z * w4.z + vb.w * w4.w;
    }

    __syncthreads();
#pragma unroll
    for (int r = 0; r < 2; ++r)
#pragma unroll
        for (int i = 0; i < 5; ++i)
            pool[(rg * 2 + r) * FG_PITCH + c0 + i] = acc[r][i] + b[c0 + i];
    __syncthreads();

    if (row0 + 64 <= n) {
        for (int i = tid; i < 64 * OUT_DIM / 4; i += 256) {
            int f = i * 4;
            int row = f / OUT_DIM;
            int col = f - row * OUT_DIM;
            *(float4*)(out + (long)(row0 + row) * OUT_DIM + col) =
                *(const float4*)(pool + row * FG_PITCH + col);
        }
    } else {
        for (int i = tid; i < 64 * OUT_DIM; i += 256) {
            int row = i / OUT_DIM;
            int col = i - row * OUT_DIM;
            if (row0 + row < n)
                out[(long)(row0 + row) * OUT_DIM + col] = pool[row * FG_PITCH + col];
        }
    }
}

// ---------------------------------------------------------------------------
extern "C" void kernel_launch(void* const* d_in, const int* in_sizes, int n_in,
                              void* d_out, int out_size, void* d_ws, size_t ws_size,
                              hipStream_t stream) {
    const float* x    = (const float*)d_in[0];
    const int*   ei   = (const int*)d_in[1];
    const float* ew   = (const float*)d_in[2];
    const float* W1   = (const float*)d_in[3];
    const float* b1   = (const float*)d_in[4];
    const float* W2   = (const float*)d_in[5];
    const float* b2   = (const float*)d_in[6];
    const float* W3   = (const float*)d_in[7];
    const float* b3   = (const float*)d_in[8];
    const float* Wlin = (const float*)d_in[9];
    const float* blin = (const float*)d_in[10];
    float* out = (float*)d_out;

    const int N = in_sizes[0] / 128;   // 50000
    const int E = in_sizes[2];         // 800000
    const int* src = ei;
    const int* dst = ei + E;
    const int NB = (N + BNODES - 1) / BNODES;   // 1563
    const int NB2 = 1600;                        // padded array length

    // Workspace: lin [N,64] | hcat [N,192] | bcnt,boff,bcur [NB2] | bsum | Wt | etmp [E]
    char* wsb = (char*)d_ws;
    float* lin  = (float*)wsb;                      wsb += (long)N * HID * 4;
    float* hcat = (float*)wsb;                      wsb += (long)N * JK_DIM * 4;
    int* bcnt   = (int*)wsb;                        wsb += NB2 * 4;
    int* boff   = (int*)wsb;                        wsb += NB2 * 4;
    int* bcur   = (int*)wsb;                        wsb += NB2 * 4;
    int* bsum   = (int*)wsb;                        wsb += 256 * 4;
    float* Wt   = (float*)wsb;                      wsb += (long)JK_DIM * OUT_DIM * 4;
    int2* etmp  = (int2*)wsb;

    dim3 blk(256);
    const int nblkB = (NB + 255) / 256;    // 7
    dim3 gE((E + 255) / 256);
    dim3 gGemm((N + 63) / 64);
    dim3 gAgg(NB);
    dim3 gFin((N + 63) / 64);

    float* h1 = hcat;           // columns [0,64)   of hcat[N,192]
    float* h2 = hcat + HID;     // columns [64,128)
    float* h3 = hcat + 2 * HID; // columns [128,192)

    // ---- bucket CSR build + W transpose (once per launch) ----
    hipMemsetAsync(bcnt, 0, NB2 * 4, stream);
    hist_bucket<<<256, blk, 0, stream>>>(dst, bcnt, E, NB);
    scan_a<<<nblkB, blk, 0, stream>>>(bcnt, boff, bsum, NB);
    scan_b<<<1, blk, 0, stream>>>(bsum, nblkB);
    scan_c<<<nblkB, blk, 0, stream>>>(boff, bsum, bcur, NB);
    fill_bucket<<<gE, blk, 0, stream>>>(src, dst, ew, bcur, etmp, E);
    transpose_w<<<(JK_DIM * OUT_DIM + 255) / 256, blk, 0, stream>>>(Wlin, Wt);

    // ---- layer 1 (K=128) ----
    gemm_tile<128><<<gGemm, blk, 0, stream>>>(x, 128, W1, lin, HID, N);
    agg_bucket<<<gAgg, blk, 0, stream>>>(lin, etmp, boff, b1, h1, N, E, NB);

    // ---- layer 2 (K=64, reads h1 inside hcat with stride 192) ----
    gemm_tile<64><<<gGemm, blk, 0, stream>>>(h1, JK_DIM, W2, lin, HID, N);
    agg_bucket<<<gAgg, blk, 0, stream>>>(lin, etmp, boff, b2, h2, N, E, NB);

    // ---- layer 3 ----
    gemm_tile<64><<<gGemm, blk, 0, stream>>>(h2, JK_DIM, W3, lin, HID, N);
    agg_bucket<<<gAgg, blk, 0, stream>>>(lin, etmp, boff, b3, h3, N, E, NB);

    // ---- JK linear ----
    final_gemm<<<gFin, blk, 0, stream>>>(hcat, Wt, blin, out, N);
}

// Round 10
// 398.429 us; speedup vs baseline: 3.0426x; 3.0426x over previous
//
#include <hip/hip_runtime.h>

// Problem constants: N=50000, E=800000, IN=128, HID=64, OUT=40
#define HID 64
#define JK_DIM 192
#define OUT_DIM 40
#define A_PITCH 68     // gemm_tile A-tile pitch: 16B aligned, max 2-way bank alias
#define W_PITCH 196    // final_gemm LDS pitch for Wt rows
#define FG_PITCH 44    // final_gemm epilogue staging pitch
#define BSH 5          // log2(nodes per bucket)
#define BNODES 32      // nodes per bucket

// bf16 helpers (RNE pack, exact unpack)
__device__ inline unsigned short f2b(float f) {
    unsigned u = __float_as_uint(f);
    unsigned r = u + 0x7FFF + ((u >> 16) & 1);
    return (unsigned short)(r >> 16);
}
__device__ inline float b2f(unsigned short u) {
    return __uint_as_float(((unsigned)u) << 16);
}

// ---------------------------------------------------------------------------
// Register-tiled GEMM: lin[64x64 tile](bf16) = h[64 x K](f32) @ W[K x 64].
// Block = 256 threads -> 16 row-groups x 16 col-groups, thread = 4x4 tile.
// Output stored as bf16 (halves aggregate gather traffic downstream).
// ---------------------------------------------------------------------------
template <int K>
__global__ __launch_bounds__(256) void gemm_tile(const float* __restrict__ h, int inStride,
                                                 const float* __restrict__ W,
                                                 unsigned short* __restrict__ outb,
                                                 int n) {
    __shared__ float As[64 * A_PITCH];
    __shared__ float Ws[64 * HID];
    int tid = threadIdx.x;
    int rg = tid >> 4;
    int cgrp = tid & 15;
    int c0 = cgrp * 4;
    int row0 = blockIdx.x * 64;
    if (row0 >= n) return;

    float acc[4][4] = {{0.f}};

    for (int kb = 0; kb < K; kb += 64) {
        for (int i = tid; i < 64 * 16; i += 256) {
            int r = i >> 4;
            int c4 = (i & 15) * 4;
            int grow = row0 + r;
            if (grow >= n) grow = n - 1;
            float4 v = *(const float4*)(h + (long)grow * inStride + kb + c4);
            *(float4*)(As + r * A_PITCH + c4) = v;
        }
        for (int i = tid; i < 64 * 16; i += 256) {
            int k = i >> 4;
            int c4 = (i & 15) * 4;
            *(float4*)(Ws + k * HID + c4) = *(const float4*)(W + (long)(kb + k) * HID + c4);
        }
        __syncthreads();
#pragma unroll 4
        for (int k = 0; k < 64; k += 4) {
            float4 w0 = *(const float4*)(Ws + (k + 0) * HID + c0);
            float4 w1 = *(const float4*)(Ws + (k + 1) * HID + c0);
            float4 w2 = *(const float4*)(Ws + (k + 2) * HID + c0);
            float4 w3 = *(const float4*)(Ws + (k + 3) * HID + c0);
#pragma unroll
            for (int r = 0; r < 4; ++r) {
                float4 a = *(const float4*)(As + (rg * 4 + r) * A_PITCH + k);
                acc[r][0] += a.x * w0.x + a.y * w1.x + a.z * w2.x + a.w * w3.x;
                acc[r][1] += a.x * w0.y + a.y * w1.y + a.z * w2.y + a.w * w3.y;
                acc[r][2] += a.x * w0.z + a.y * w1.z + a.z * w2.z + a.w * w3.z;
                acc[r][3] += a.x * w0.w + a.y * w1.w + a.z * w2.w + a.w * w3.w;
            }
        }
        __syncthreads();
    }
#pragma unroll
    for (int r = 0; r < 4; ++r) {
        int grow = row0 + rg * 4 + r;
        if (grow < n) {
            ushort4 o;
            o.x = f2b(acc[r][0]);
            o.y = f2b(acc[r][1]);
            o.z = f2b(acc[r][2]);
            o.w = f2b(acc[r][3]);
            *(ushort4*)(outb + (long)grow * HID + c0) = o;
        }
    }
}

// ---------------------------------------------------------------------------
// Bucket histogram: LDS-privatized counts of dst>>BSH.
// ---------------------------------------------------------------------------
__global__ __launch_bounds__(256) void hist_bucket(const int* __restrict__ dst,
                                                   int* __restrict__ bcnt,
                                                   int E, int nb) {
    __shared__ int h[1600];
    for (int i = threadIdx.x; i < nb; i += 256) h[i] = 0;
    __syncthreads();
    for (int e = blockIdx.x * 256 + threadIdx.x; e < E; e += gridDim.x * 256)
        atomicAdd(&h[dst[e] >> BSH], 1);
    __syncthreads();
    for (int i = threadIdx.x; i < nb; i += 256) {
        int v = h[i];
        if (v) atomicAdd(&bcnt[i], v);
    }
}

// ---------------------------------------------------------------------------
// Exclusive scan (3 passes) over nb <= 256*256 elements.
// ---------------------------------------------------------------------------
__global__ __launch_bounds__(256) void scan_a(const int* __restrict__ deg,
                                              int* __restrict__ off,
                                              int* __restrict__ bsum, int n) {
    __shared__ int tmp[256];
    int i = blockIdx.x * 256 + threadIdx.x;
    int v = (i < n) ? deg[i] : 0;
    tmp[threadIdx.x] = v;
    __syncthreads();
    for (int d = 1; d < 256; d <<= 1) {
        int t = (threadIdx.x >= d) ? tmp[threadIdx.x - d] : 0;
        __syncthreads();
        tmp[threadIdx.x] += t;
        __syncthreads();
    }
    if (i < n) off[i] = tmp[threadIdx.x] - v;
    if (threadIdx.x == 255) bsum[blockIdx.x] = tmp[255];
}

__global__ __launch_bounds__(256) void scan_b(int* __restrict__ bsum, int nblk) {
    __shared__ int tmp[256];
    int v = (threadIdx.x < nblk) ? bsum[threadIdx.x] : 0;
    tmp[threadIdx.x] = v;
    __syncthreads();
    for (int d = 1; d < 256; d <<= 1) {
        int t = (threadIdx.x >= d) ? tmp[threadIdx.x - d] : 0;
        __syncthreads();
        tmp[threadIdx.x] += t;
        __syncthreads();
    }
    if (threadIdx.x < nblk) bsum[threadIdx.x] = tmp[threadIdx.x] - v;
}

__global__ __launch_bounds__(256) void scan_c(int* __restrict__ off,
                                              const int* __restrict__ bsum,
                                              int* __restrict__ pos, int n) {
    int i = blockIdx.x * 256 + threadIdx.x;
    if (i >= n) return;
    int o = off[i] + bsum[blockIdx.x];
    off[i] = o;
    pos[i] = o;
}

// ---------------------------------------------------------------------------
// Bucket scatter: record = (src | dstLow<<20, weight) into the dst bucket's
// region. 1563 concurrent cursors -> writes cluster into advancing windows.
// ---------------------------------------------------------------------------
__global__ __launch_bounds__(256) void fill_bucket(const int* __restrict__ src,
                                                   const int* __restrict__ dst,
                                                   const float* __restrict__ ew,
                                                   int* __restrict__ bcur,
                                                   int2* __restrict__ etmp, int E) {
    int e = blockIdx.x * 256 + threadIdx.x;
    if (e >= E) return;
    int d = dst[e];
    int p = atomicAdd(&bcur[d >> BSH], 1);
    int2 v;
    v.x = src[e] | ((d & (BNODES - 1)) << 20);
    v.y = __float_as_int(ew[e]);
    etmp[p] = v;
}

// ---------------------------------------------------------------------------
// Exact CSR from buckets: one block per bucket. LDS histogram of the 32
// nodes, serial scan, then node-sorted rewrite into ecsr (writes stay inside
// the bucket's ~4KB window -> L2-coalesced). Emits exact deg/off.
// ---------------------------------------------------------------------------
__global__ __launch_bounds__(256) void csr_from_buckets(const int2* __restrict__ etmp,
                                                        const int* __restrict__ boff,
                                                        int* __restrict__ deg,
                                                        int* __restrict__ off,
                                                        int2* __restrict__ ecsr,
                                                        int n, int E, int nb) {
    __shared__ int cnt[BNODES];
    __shared__ int base[BNODES];
    __shared__ int cur[BNODES];
    int b = blockIdx.x;
    int tid = threadIdx.x;
    int s0 = boff[b];
    int e0 = (b + 1 < nb) ? boff[b + 1] : E;
    if (tid < BNODES) cnt[tid] = 0;
    __syncthreads();
    for (int i = s0 + tid; i < e0; i += 256)
        atomicAdd(&cnt[(etmp[i].x >> 20) & (BNODES - 1)], 1);
    __syncthreads();
    if (tid == 0) {
        int a = 0;
        for (int j = 0; j < BNODES; ++j) { base[j] = a; cur[j] = a; a += cnt[j]; }
    }
    __syncthreads();
    if (tid < BNODES) {
        int node = (b << BSH) + tid;
        if (node < n) {
            deg[node] = cnt[tid];
            off[node] = s0 + base[tid];
        }
    }
    for (int i = s0 + tid; i < e0; i += 256) {
        int2 r = etmp[i];
        int d = (r.x >> 20) & (BNODES - 1);
        int p = atomicAdd(&cur[d], 1);
        ecsr[s0 + p] = make_int2(r.x & 0xFFFFF, r.y);
    }
}

// ---------------------------------------------------------------------------
// Aggregate + bias + ReLU. One 16-lane group per node; 4-stream software
// pipeline with metadata prefetched a quartet ahead -> 16 independent
// gathers in flight per wave. lin is bf16: lane reads ushort4 (8B), a
// 16-lane group covers the full 128B row. Output row written f32 into hcat.
// ---------------------------------------------------------------------------
__global__ __launch_bounds__(256) void aggregate(const unsigned short* __restrict__ linb,
                                                 const int2* __restrict__ ecsr,
                                                 const int* __restrict__ off,
                                                 const int* __restrict__ deg,
                                                 const float* __restrict__ bias,
                                                 float* __restrict__ hout, int n) {
    int cl = threadIdx.x & 15;
    float4 b4 = *(const float4*)(bias + cl * 4);
    int grp = (blockIdx.x * 256 + threadIdx.x) >> 4;
    int ngrp = (gridDim.x * 256) >> 4;
    for (int node = grp; node < n; node += ngrp) {
        int start = off[node];
        int cnt = deg[node];
        float ax = 0.f, ay = 0.f, az = 0.f, aw = 0.f;

        int s[4];
        float w[4];
#pragma unroll
        for (int t = 0; t < 4; ++t) {
            s[t] = 0; w[t] = 0.f;
            if (t < cnt) {
                int2 m = ecsr[start + t];
                s[t] = m.x; w[t] = __int_as_float(m.y);
            }
        }
        for (int bb = 0; bb < cnt; bb += 4) {
            int s2[4];
            float w2[4];
#pragma unroll
            for (int t = 0; t < 4; ++t) {
                int e = bb + 4 + t;
                s2[t] = 0; w2[t] = 0.f;
                if (e < cnt) {
                    int2 m = ecsr[start + e];
                    s2[t] = m.x; w2[t] = __int_as_float(m.y);
                }
            }
            ushort4 u0 = *(const ushort4*)(linb + (long)s[0] * HID + cl * 4);
            ushort4 u1 = *(const ushort4*)(linb + (long)s[1] * HID + cl * 4);
            ushort4 u2 = *(const ushort4*)(linb + (long)s[2] * HID + cl * 4);
            ushort4 u3 = *(const ushort4*)(linb + (long)s[3] * HID + cl * 4);
            ax += b2f(u0.x) * w[0] + b2f(u1.x) * w[1] + b2f(u2.x) * w[2] + b2f(u3.x) * w[3];
            ay += b2f(u0.y) * w[0] + b2f(u1.y) * w[1] + b2f(u2.y) * w[2] + b2f(u3.y) * w[3];
            az += b2f(u0.z) * w[0] + b2f(u1.z) * w[1] + b2f(u2.z) * w[2] + b2f(u3.z) * w[3];
            aw += b2f(u0.w) * w[0] + b2f(u1.w) * w[1] + b2f(u2.w) * w[2] + b2f(u3.w) * w[3];
#pragma unroll
            for (int t = 0; t < 4; ++t) { s[t] = s2[t]; w[t] = w2[t]; }
        }

        float4 o;
        o.x = fmaxf(ax + b4.x, 0.f);
        o.y = fmaxf(ay + b4.y, 0.f);
        o.z = fmaxf(az + b4.z, 0.f);
        o.w = fmaxf(aw + b4.w, 0.f);
        *(float4*)(hout + (long)node * JK_DIM + cl * 4) = o;
    }
}

// ---------------------------------------------------------------------------
// Transpose Wlin[192,40] -> Wt[40,192] (runs once, stays L2-hot).
// ---------------------------------------------------------------------------
__global__ __launch_bounds__(256) void transpose_w(const float* __restrict__ W,
                                                   float* __restrict__ Wt) {
    int i = blockIdx.x * 256 + threadIdx.x;
    if (i < JK_DIM * OUT_DIM) {
        int k = i / OUT_DIM;
        int c = i - k * OUT_DIM;
        Wt[c * JK_DIM + k] = W[i];
    }
}

// ---------------------------------------------------------------------------
// Final: out[n,40] = hcat[n,192] @ Wlin[192,40] + blin.
// 64-row tile per 256-thread block; thread = 2 rows x 5 cols; Wt in LDS at
// pitch 196; pool reused as epilogue staging for coalesced float4 stores.
// ---------------------------------------------------------------------------
__global__ __launch_bounds__(256) void final_gemm(const float* __restrict__ hcat,
                                                  const float* __restrict__ Wt,
                                                  const float* __restrict__ b,
                                                  float* __restrict__ out, int n) {
    __shared__ float pool[OUT_DIM * W_PITCH];  // 31360 B
    int tid = threadIdx.x;
    for (int i = tid; i < OUT_DIM * 48; i += 256) {
        int c = i / 48;
        int q = (i - c * 48) * 4;
        *(float4*)(pool + c * W_PITCH + q) = *(const float4*)(Wt + (long)c * JK_DIM + q);
    }
    __syncthreads();

    int rg = tid >> 3;
    int cg = tid & 7;
    int c0 = cg * 5;
    int row0 = blockIdx.x * 64;
    int r0 = row0 + rg * 2;
    int ra = r0 < n ? r0 : n - 1;
    int rb = r0 + 1 < n ? r0 + 1 : n - 1;
    const float* ha = hcat + (long)ra * JK_DIM;
    const float* hb = hcat + (long)rb * JK_DIM;

    float acc[2][5];
#pragma unroll
    for (int r = 0; r < 2; ++r)
#pragma unroll
        for (int i = 0; i < 5; ++i) acc[r][i] = 0.f;

#pragma unroll 4
    for (int k = 0; k < JK_DIM; k += 4) {
        float4 va = *(const float4*)(ha + k);
        float4 vb = *(const float4*)(hb + k);
        float4 w0 = *(const float4*)(pool + (c0 + 0) * W_PITCH + k);
        float4 w1 = *(const float4*)(pool + (c0 + 1) * W_PITCH + k);
        float4 w2 = *(const float4*)(pool + (c0 + 2) * W_PITCH + k);
        float4 w3 = *(const float4*)(pool + (c0 + 3) * W_PITCH + k);
        float4 w4 = *(const float4*)(pool + (c0 + 4) * W_PITCH + k);
        acc[0][0] += va.x * w0.x + va.y * w0.y + va.z * w0.z + va.w * w0.w;
        acc[0][1] += va.x * w1.x + va.y * w1.y + va.z * w1.z + va.w * w1.w;
        acc[0][2] += va.x * w2.x + va.y * w2.y + va.z * w2.z + va.w * w2.w;
        acc[0][3] += va.x * w3.x + va.y * w3.y + va.z * w3.z + va.w * w3.w;
        acc[0][4] += va.x * w4.x + va.y * w4.y + va.z * w4.z + va.w * w4.w;
        acc[1][0] += vb.x * w0.x + vb.y * w0.y + vb.z * w0.z + vb.w * w0.w;
        acc[1][1] += vb.x * w1.x + vb.y * w1.y + vb.z * w1.z + vb.w * w1.w;
        acc[1][2] += vb.x * w2.x + vb.y * w2.y + vb.z * w2.z + vb.w * w2.w;
        acc[1][3] += vb.x * w3.x + vb.y * w3.y + vb.z * w3.z + vb.w * w3.w;
        acc[1][4] += vb.x * w4.x + vb.y * w4.y + vb.z * w4.z + vb.w * w4.w;
    }

    __syncthreads();
#pragma unroll
    for (int r = 0; r < 2; ++r)
#pragma unroll
        for (int i = 0; i < 5; ++i)
            pool[(rg * 2 + r) * FG_PITCH + c0 + i] = acc[r][i] + b[c0 + i];
    __syncthreads();

    if (row0 + 64 <= n) {
        for (int i = tid; i < 64 * OUT_DIM / 4; i += 256) {
            int f = i * 4;
            int row = f / OUT_DIM;
            int col = f - row * OUT_DIM;
            *(float4*)(out + (long)(row0 + row) * OUT_DIM + col) =
                *(const float4*)(pool + row * FG_PITCH + col);
        }
    } else {
        for (int i = tid; i < 64 * OUT_DIM; i += 256) {
            int row = i / OUT_DIM;
            int col = i - row * OUT_DIM;
            if (row0 + row < n)
                out[(long)(row0 + row) * OUT_DIM + col] = pool[row * FG_PITCH + col];
        }
    }
}

// ---------------------------------------------------------------------------
extern "C" void kernel_launch(void* const* d_in, const int* in_sizes, int n_in,
                              void* d_out, int out_size, void* d_ws, size_t ws_size,
                              hipStream_t stream) {
    const float* x    = (const float*)d_in[0];
    const int*   ei   = (const int*)d_in[1];
    const float* ew   = (const float*)d_in[2];
    const float* W1   = (const float*)d_in[3];
    const float* b1   = (const float*)d_in[4];
    const float* W2   = (const float*)d_in[5];
    const float* b2   = (const float*)d_in[6];
    const float* W3   = (const float*)d_in[7];
    const float* b3   = (const float*)d_in[8];
    const float* Wlin = (const float*)d_in[9];
    const float* blin = (const float*)d_in[10];
    float* out = (float*)d_out;

    const int N = in_sizes[0] / 128;   // 50000
    const int E = in_sizes[2];         // 800000
    const int* src = ei;
    const int* dst = ei + E;
    const int NB = (N + BNODES - 1) / BNODES;   // 1563
    const int NB2 = 1600;

    // Workspace: linb(bf16) | hcat | deg,off | bcnt,boff,bcur | bsum | Wt | etmp | ecsr
    char* wsb = (char*)d_ws;
    unsigned short* linb = (unsigned short*)wsb;    wsb += (long)N * HID * 2;
    float* hcat = (float*)wsb;                      wsb += (long)N * JK_DIM * 4;
    int* deg    = (int*)wsb;                        wsb += (long)N * 4;
    int* off    = (int*)wsb;                        wsb += (long)N * 4;
    int* bcnt   = (int*)wsb;                        wsb += NB2 * 4;
    int* boff   = (int*)wsb;                        wsb += NB2 * 4;
    int* bcur   = (int*)wsb;                        wsb += NB2 * 4;
    int* bsum   = (int*)wsb;                        wsb += 256 * 4;
    float* Wt   = (float*)wsb;                      wsb += (long)JK_DIM * OUT_DIM * 4;
    int2* etmp  = (int2*)wsb;                       wsb += (long)E * 8;
    int2* ecsr  = (int2*)wsb;

    dim3 blk(256);
    const int nblkB = (NB + 255) / 256;    // 7
    dim3 gE((E + 255) / 256);
    dim3 gGemm((N + 63) / 64);
    dim3 gAgg((N + 15) / 16);
    dim3 gFin((N + 63) / 64);

    float* h1 = hcat;           // columns [0,64)   of hcat[N,192]
    float* h2 = hcat + HID;     // columns [64,128)
    float* h3 = hcat + 2 * HID; // columns [128,192)

    // ---- bucketed exact-CSR build + W transpose (once per launch) ----
    hipMemsetAsync(bcnt, 0, NB2 * 4, stream);
    hist_bucket<<<256, blk, 0, stream>>>(dst, bcnt, E, NB);
    scan_a<<<nblkB, blk, 0, stream>>>(bcnt, boff, bsum, NB);
    scan_b<<<1, blk, 0, stream>>>(bsum, nblkB);
    scan_c<<<nblkB, blk, 0, stream>>>(boff, bsum, bcur, NB);
    fill_bucket<<<gE, blk, 0, stream>>>(src, dst, ew, bcur, etmp, E);
    csr_from_buckets<<<NB, blk, 0, stream>>>(etmp, boff, deg, off, ecsr, N, E, NB);
    transpose_w<<<(JK_DIM * OUT_DIM + 255) / 256, blk, 0, stream>>>(Wlin, Wt);

    // ---- layer 1 (K=128) ----
    gemm_tile<128><<<gGemm, blk, 0, stream>>>(x, 128, W1, linb, N);
    aggregate<<<gAgg, blk, 0, stream>>>(linb, ecsr, off, deg, b1, h1, N);

    // ---- layer 2 (K=64, reads h1 inside hcat with stride 192) ----
    gemm_tile<64><<<gGemm, blk, 0, stream>>>(h1, JK_DIM, W2, linb, N);
    aggregate<<<gAgg, blk, 0, stream>>>(linb, ecsr, off, deg, b2, h2, N);

    // ---- layer 3 ----
    gemm_tile<64><<<gGemm, blk, 0, stream>>>(h2, JK_DIM, W3, linb, N);
    aggregate<<<gAgg, blk, 0, stream>>>(linb, ecsr, off, deg, b3, h3, N);

    // ---- JK linear ----
    final_gemm<<<gFin, blk, 0, stream>>>(hcat, Wt, blin, out, N);
}

// Round 11
// 340.411 us; speedup vs baseline: 3.5612x; 1.1704x over previous
//
#include <hip/hip_runtime.h>

// Problem constants: N=50000, E=800000, IN=128, HID=64, OUT=40
#define HID 64
#define JK_DIM 192
#define OUT_DIM 40
#define A_PITCH 68     // gemm_tile A-tile pitch: 16B aligned, max 2-way bank alias
#define W_PITCH 196    // final_gemm LDS pitch for Wt rows
#define FG_PITCH 44    // final_gemm epilogue staging pitch

// bf16 helpers (RNE pack, exact unpack)
__device__ inline unsigned short f2b(float f) {
    unsigned u = __float_as_uint(f);
    unsigned r = u + 0x7FFF + ((u >> 16) & 1);
    return (unsigned short)(r >> 16);
}
__device__ inline float b2f(unsigned short u) {
    return __uint_as_float(((unsigned)u) << 16);
}

// ---------------------------------------------------------------------------
// Register-tiled GEMM: lin[64x64 tile](bf16) = h[64 x K](f32) @ W[K x 64].
// Block = 256 threads -> 16 row-groups x 16 col-groups, thread = 4x4 tile.
// ---------------------------------------------------------------------------
template <int K>
__global__ __launch_bounds__(256) void gemm_tile(const float* __restrict__ h, int inStride,
                                                 const float* __restrict__ W,
                                                 unsigned short* __restrict__ outb,
                                                 int n) {
    __shared__ float As[64 * A_PITCH];
    __shared__ float Ws[64 * HID];
    int tid = threadIdx.x;
    int rg = tid >> 4;
    int cgrp = tid & 15;
    int c0 = cgrp * 4;
    int row0 = blockIdx.x * 64;
    if (row0 >= n) return;

    float acc[4][4] = {{0.f}};

    for (int kb = 0; kb < K; kb += 64) {
        for (int i = tid; i < 64 * 16; i += 256) {
            int r = i >> 4;
            int c4 = (i & 15) * 4;
            int grow = row0 + r;
            if (grow >= n) grow = n - 1;
            float4 v = *(const float4*)(h + (long)grow * inStride + kb + c4);
            *(float4*)(As + r * A_PITCH + c4) = v;
        }
        for (int i = tid; i < 64 * 16; i += 256) {
            int k = i >> 4;
            int c4 = (i & 15) * 4;
            *(float4*)(Ws + k * HID + c4) = *(const float4*)(W + (long)(kb + k) * HID + c4);
        }
        __syncthreads();
#pragma unroll 4
        for (int k = 0; k < 64; k += 4) {
            float4 w0 = *(const float4*)(Ws + (k + 0) * HID + c0);
            float4 w1 = *(const float4*)(Ws + (k + 1) * HID + c0);
            float4 w2 = *(const float4*)(Ws + (k + 2) * HID + c0);
            float4 w3 = *(const float4*)(Ws + (k + 3) * HID + c0);
#pragma unroll
            for (int r = 0; r < 4; ++r) {
                float4 a = *(const float4*)(As + (rg * 4 + r) * A_PITCH + k);
                acc[r][0] += a.x * w0.x + a.y * w1.x + a.z * w2.x + a.w * w3.x;
                acc[r][1] += a.x * w0.y + a.y * w1.y + a.z * w2.y + a.w * w3.y;
                acc[r][2] += a.x * w0.z + a.y * w1.z + a.z * w2.z + a.w * w3.z;
                acc[r][3] += a.x * w0.w + a.y * w1.w + a.z * w2.w + a.w * w3.w;
            }
        }
        __syncthreads();
    }
#pragma unroll
    for (int r = 0; r < 4; ++r) {
        int grow = row0 + rg * 4 + r;
        if (grow < n) {
            ushort4 o;
            o.x = f2b(acc[r][0]);
            o.y = f2b(acc[r][1]);
            o.z = f2b(acc[r][2]);
            o.w = f2b(acc[r][3]);
            *(ushort4*)(outb + (long)grow * HID + c0) = o;
        }
    }
}

// ---------------------------------------------------------------------------
// Exact CSR build: histogram of dst (50k counters, 16 RMWs/addr -> no atomic
// chain), 3-pass exclusive scan, 50k-cursor slot fill.
// ---------------------------------------------------------------------------
__global__ __launch_bounds__(256) void hist_dst(const int* __restrict__ dst,
                                                int* __restrict__ deg, int E) {
    int e = blockIdx.x * 256 + threadIdx.x;
    if (e < E) atomicAdd(&deg[dst[e]], 1);
}

__global__ __launch_bounds__(256) void scan_a(const int* __restrict__ deg,
                                              int* __restrict__ off,
                                              int* __restrict__ bsum, int n) {
    __shared__ int tmp[256];
    int i = blockIdx.x * 256 + threadIdx.x;
    int v = (i < n) ? deg[i] : 0;
    tmp[threadIdx.x] = v;
    __syncthreads();
    for (int d = 1; d < 256; d <<= 1) {
        int t = (threadIdx.x >= d) ? tmp[threadIdx.x - d] : 0;
        __syncthreads();
        tmp[threadIdx.x] += t;
        __syncthreads();
    }
    if (i < n) off[i] = tmp[threadIdx.x] - v;
    if (threadIdx.x == 255) bsum[blockIdx.x] = tmp[255];
}

__global__ __launch_bounds__(256) void scan_b(int* __restrict__ bsum, int nblk) {
    __shared__ int tmp[256];
    int v = (threadIdx.x < nblk) ? bsum[threadIdx.x] : 0;
    tmp[threadIdx.x] = v;
    __syncthreads();
    for (int d = 1; d < 256; d <<= 1) {
        int t = (threadIdx.x >= d) ? tmp[threadIdx.x - d] : 0;
        __syncthreads();
        tmp[threadIdx.x] += t;
        __syncthreads();
    }
    if (threadIdx.x < nblk) bsum[threadIdx.x] = tmp[threadIdx.x] - v;
}

__global__ __launch_bounds__(256) void scan_c(int* __restrict__ off,
                                              const int* __restrict__ bsum,
                                              int* __restrict__ pos, int n) {
    int i = blockIdx.x * 256 + threadIdx.x;
    if (i >= n) return;
    int o = off[i] + bsum[blockIdx.x];
    off[i] = o;
    pos[i] = o;
}

__global__ __launch_bounds__(256) void fill_csr(const int* __restrict__ src,
                                                const int* __restrict__ dst,
                                                const float* __restrict__ ew,
                                                int* __restrict__ pos,
                                                int2* __restrict__ ecsr, int E) {
    int e = blockIdx.x * 256 + threadIdx.x;
    if (e >= E) return;
    int p = atomicAdd(&pos[dst[e]], 1);
    int2 v;
    v.x = src[e];
    v.y = __float_as_int(ew[e]);
    ecsr[p] = v;
}

// ---------------------------------------------------------------------------
// Aggregate + bias + ReLU. One 16-lane group per node; 4-stream software
// pipeline with metadata prefetched a quartet ahead -> 16 independent
// gathers in flight per wave. lin is bf16: lane reads ushort4 (8B), a
// 16-lane group covers the full 128B row. Output row written f32 into hcat.
// ---------------------------------------------------------------------------
__global__ __launch_bounds__(256) void aggregate(const unsigned short* __restrict__ linb,
                                                 const int2* __restrict__ ecsr,
                                                 const int* __restrict__ off,
                                                 const int* __restrict__ deg,
                                                 const float* __restrict__ bias,
                                                 float* __restrict__ hout, int n) {
    int cl = threadIdx.x & 15;
    float4 b4 = *(const float4*)(bias + cl * 4);
    int grp = (blockIdx.x * 256 + threadIdx.x) >> 4;
    int ngrp = (gridDim.x * 256) >> 4;
    for (int node = grp; node < n; node += ngrp) {
        int start = off[node];
        int cnt = deg[node];
        float ax = 0.f, ay = 0.f, az = 0.f, aw = 0.f;

        int s[4];
        float w[4];
#pragma unroll
        for (int t = 0; t < 4; ++t) {
            s[t] = 0; w[t] = 0.f;
            if (t < cnt) {
                int2 m = ecsr[start + t];
                s[t] = m.x; w[t] = __int_as_float(m.y);
            }
        }
        for (int bb = 0; bb < cnt; bb += 4) {
            int s2[4];
            float w2[4];
#pragma unroll
            for (int t = 0; t < 4; ++t) {
                int e = bb + 4 + t;
                s2[t] = 0; w2[t] = 0.f;
                if (e < cnt) {
                    int2 m = ecsr[start + e];
                    s2[t] = m.x; w2[t] = __int_as_float(m.y);
                }
            }
            ushort4 u0 = *(const ushort4*)(linb + (long)s[0] * HID + cl * 4);
            ushort4 u1 = *(const ushort4*)(linb + (long)s[1] * HID + cl * 4);
            ushort4 u2 = *(const ushort4*)(linb + (long)s[2] * HID + cl * 4);
            ushort4 u3 = *(const ushort4*)(linb + (long)s[3] * HID + cl * 4);
            ax += b2f(u0.x) * w[0] + b2f(u1.x) * w[1] + b2f(u2.x) * w[2] + b2f(u3.x) * w[3];
            ay += b2f(u0.y) * w[0] + b2f(u1.y) * w[1] + b2f(u2.y) * w[2] + b2f(u3.y) * w[3];
            az += b2f(u0.z) * w[0] + b2f(u1.z) * w[1] + b2f(u2.z) * w[2] + b2f(u3.z) * w[3];
            aw += b2f(u0.w) * w[0] + b2f(u1.w) * w[1] + b2f(u2.w) * w[2] + b2f(u3.w) * w[3];
#pragma unroll
            for (int t = 0; t < 4; ++t) { s[t] = s2[t]; w[t] = w2[t]; }
        }

        float4 o;
        o.x = fmaxf(ax + b4.x, 0.f);
        o.y = fmaxf(ay + b4.y, 0.f);
        o.z = fmaxf(az + b4.z, 0.f);
        o.w = fmaxf(aw + b4.w, 0.f);
        *(float4*)(hout + (long)node * JK_DIM + cl * 4) = o;
    }
}

// ---------------------------------------------------------------------------
// Transpose Wlin[192,40] -> Wt[40,192] (runs once, stays L2-hot).
// ---------------------------------------------------------------------------
__global__ __launch_bounds__(256) void transpose_w(const float* __restrict__ W,
                                                   float* __restrict__ Wt) {
    int i = blockIdx.x * 256 + threadIdx.x;
    if (i < JK_DIM * OUT_DIM) {
        int k = i / OUT_DIM;
        int c = i - k * OUT_DIM;
        Wt[c * JK_DIM + k] = W[i];
    }
}

// ---------------------------------------------------------------------------
// Final: out[n,40] = hcat[n,192] @ Wlin[192,40] + blin.
// 64-row tile per 256-thread block; thread = 2 rows x 5 cols; Wt in LDS at
// pitch 196; pool reused as epilogue staging for coalesced float4 stores.
// ---------------------------------------------------------------------------
__global__ __launch_bounds__(256) void final_gemm(const float* __restrict__ hcat,
                                                  const float* __restrict__ Wt,
                                                  const float* __restrict__ b,
                                                  float* __restrict__ out, int n) {
    __shared__ float pool[OUT_DIM * W_PITCH];  // 31360 B
    int tid = threadIdx.x;
    for (int i = tid; i < OUT_DIM * 48; i += 256) {
        int c = i / 48;
        int q = (i - c * 48) * 4;
        *(float4*)(pool + c * W_PITCH + q) = *(const float4*)(Wt + (long)c * JK_DIM + q);
    }
    __syncthreads();

    int rg = tid >> 3;
    int cg = tid & 7;
    int c0 = cg * 5;
    int row0 = blockIdx.x * 64;
    int r0 = row0 + rg * 2;
    int ra = r0 < n ? r0 : n - 1;
    int rb = r0 + 1 < n ? r0 + 1 : n - 1;
    const float* ha = hcat + (long)ra * JK_DIM;
    const float* hb = hcat + (long)rb * JK_DIM;

    float acc[2][5];
#pragma unroll
    for (int r = 0; r < 2; ++r)
#pragma unroll
        for (int i = 0; i < 5; ++i) acc[r][i] = 0.f;

#pragma unroll 4
    for (int k = 0; k < JK_DIM; k += 4) {
        float4 va = *(const float4*)(ha + k);
        float4 vb = *(const float4*)(hb + k);
        float4 w0 = *(const float4*)(pool + (c0 + 0) * W_PITCH + k);
        float4 w1 = *(const float4*)(pool + (c0 + 1) * W_PITCH + k);
        float4 w2 = *(const float4*)(pool + (c0 + 2) * W_PITCH + k);
        float4 w3 = *(const float4*)(pool + (c0 + 3) * W_PITCH + k);
        float4 w4 = *(const float4*)(pool + (c0 + 4) * W_PITCH + k);
        acc[0][0] += va.x * w0.x + va.y * w0.y + va.z * w0.z + va.w * w0.w;
        acc[0][1] += va.x * w1.x + va.y * w1.y + va.z * w1.z + va.w * w1.w;
        acc[0][2] += va.x * w2.x + va.y * w2.y + va.z * w2.z + va.w * w2.w;
        acc[0][3] += va.x * w3.x + va.y * w3.y + va.z * w3.z + va.w * w3.w;
        acc[0][4] += va.x * w4.x + va.y * w4.y + va.z * w4.z + va.w * w4.w;
        acc[1][0] += vb.x * w0.x + vb.y * w0.y + vb.z * w0.z + vb.w * w0.w;
        acc[1][1] += vb.x * w1.x + vb.y * w1.y + vb.z * w1.z + vb.w * w1.w;
        acc[1][2] += vb.x * w2.x + vb.y * w2.y + vb.z * w2.z + vb.w * w2.w;
        acc[1][3] += vb.x * w3.x + vb.y * w3.y + vb.z * w3.z + vb.w * w3.w;
        acc[1][4] += vb.x * w4.x + vb.y * w4.y + vb.z * w4.z + vb.w * w4.w;
    }

    __syncthreads();
#pragma unroll
    for (int r = 0; r < 2; ++r)
#pragma unroll
        for (int i = 0; i < 5; ++i)
            pool[(rg * 2 + r) * FG_PITCH + c0 + i] = acc[r][i] + b[c0 + i];
    __syncthreads();

    if (row0 + 64 <= n) {
        for (int i = tid; i < 64 * OUT_DIM / 4; i += 256) {
            int f = i * 4;
            int row = f / OUT_DIM;
            int col = f - row * OUT_DIM;
            *(float4*)(out + (long)(row0 + row) * OUT_DIM + col) =
                *(const float4*)(pool + row * FG_PITCH + col);
        }
    } else {
        for (int i = tid; i < 64 * OUT_DIM; i += 256) {
            int row = i / OUT_DIM;
            int col = i - row * OUT_DIM;
            if (row0 + row < n)
                out[(long)(row0 + row) * OUT_DIM + col] = pool[row * FG_PITCH + col];
        }
    }
}

// ---------------------------------------------------------------------------
extern "C" void kernel_launch(void* const* d_in, const int* in_sizes, int n_in,
                              void* d_out, int out_size, void* d_ws, size_t ws_size,
                              hipStream_t stream) {
    const float* x    = (const float*)d_in[0];
    const int*   ei   = (const int*)d_in[1];
    const float* ew   = (const float*)d_in[2];
    const float* W1   = (const float*)d_in[3];
    const float* b1   = (const float*)d_in[4];
    const float* W2   = (const float*)d_in[5];
    const float* b2   = (const float*)d_in[6];
    const float* W3   = (const float*)d_in[7];
    const float* b3   = (const float*)d_in[8];
    const float* Wlin = (const float*)d_in[9];
    const float* blin = (const float*)d_in[10];
    float* out = (float*)d_out;

    const int N = in_sizes[0] / 128;   // 50000
    const int E = in_sizes[2];         // 800000
    const int* src = ei;
    const int* dst = ei + E;

    // Workspace: linb(bf16) | hcat | deg,off,pos [N] | bsum | Wt | ecsr [E]
    char* wsb = (char*)d_ws;
    unsigned short* linb = (unsigned short*)wsb;    wsb += (long)N * HID * 2;
    float* hcat = (float*)wsb;                      wsb += (long)N * JK_DIM * 4;
    int* deg    = (int*)wsb;                        wsb += (long)N * 4;
    int* off    = (int*)wsb;                        wsb += (long)N * 4;
    int* pos    = (int*)wsb;                        wsb += (long)N * 4;
    int* bsum   = (int*)wsb;                        wsb += 256 * 4;
    float* Wt   = (float*)wsb;                      wsb += (long)JK_DIM * OUT_DIM * 4;
    int2* ecsr  = (int2*)wsb;

    dim3 blk(256);
    const int nblkN = (N + 255) / 256;     // 196
    dim3 gN(nblkN);
    dim3 gE((E + 255) / 256);
    dim3 gGemm((N + 63) / 64);
    dim3 gAgg((N + 15) / 16);
    dim3 gFin((N + 63) / 64);

    float* h1 = hcat;           // columns [0,64)   of hcat[N,192]
    float* h2 = hcat + HID;     // columns [64,128)
    float* h3 = hcat + 2 * HID; // columns [128,192)

    // ---- exact CSR build + W transpose (once per launch) ----
    hipMemsetAsync(deg, 0, (long)N * 4, stream);
    hist_dst<<<gE, blk, 0, stream>>>(dst, deg, E);
    scan_a<<<gN, blk, 0, stream>>>(deg, off, bsum, N);
    scan_b<<<1, blk, 0, stream>>>(bsum, nblkN);
    scan_c<<<gN, blk, 0, stream>>>(off, bsum, pos, N);
    fill_csr<<<gE, blk, 0, stream>>>(src, dst, ew, pos, ecsr, E);
    transpose_w<<<(JK_DIM * OUT_DIM + 255) / 256, blk, 0, stream>>>(Wlin, Wt);

    // ---- layer 1 (K=128) ----
    gemm_tile<128><<<gGemm, blk, 0, stream>>>(x, 128, W1, linb, N);
    aggregate<<<gAgg, blk, 0, stream>>>(linb, ecsr, off, deg, b1, h1, N);

    // ---- layer 2 (K=64, reads h1 inside hcat with stride 192) ----
    gemm_tile<64><<<gGemm, blk, 0, stream>>>(h1, JK_DIM, W2, linb, N);
    aggregate<<<gAgg, blk, 0, stream>>>(linb, ecsr, off, deg, b2, h2, N);

    // ---- layer 3 ----
    gemm_tile<64><<<gGemm, blk, 0, stream>>>(h2, JK_DIM, W3, linb, N);
    aggregate<<<gAgg, blk, 0, stream>>>(linb, ecsr, off, deg, b3, h3, N);

    // ---- JK linear ----
    final_gemm<<<gFin, blk, 0, stream>>>(hcat, Wt, blin, out, N);
}

// Round 12
// 330.631 us; speedup vs baseline: 3.6665x; 1.0296x over previous
//
#include <hip/hip_runtime.h>

// Problem constants: N=50000, E=800000, IN=128, HID=64, OUT=40
#define HID 64
#define JK_DIM 192
#define OUT_DIM 40
#define A_PITCH 68     // gemm_tile A-tile pitch: 16B aligned, max 2-way bank alias
#define W_PITCH 196    // final_gemm LDS pitch for Wt rows
#define FG_PITCH 44    // final_gemm epilogue staging pitch

// bf16 helpers (RNE pack, exact unpack)
__device__ inline unsigned short f2b(float f) {
    unsigned u = __float_as_uint(f);
    unsigned r = u + 0x7FFF + ((u >> 16) & 1);
    return (unsigned short)(r >> 16);
}
__device__ inline float b2f(unsigned short u) {
    return __uint_as_float(((unsigned)u) << 16);
}

// ---------------------------------------------------------------------------
// Register-tiled GEMM: lin[64x64 tile](bf16) = h[64 x K](f32) @ W[K x 64].
// Block = 256 threads -> 16 row-groups x 16 col-groups, thread = 4x4 tile.
// ---------------------------------------------------------------------------
template <int K>
__global__ __launch_bounds__(256) void gemm_tile(const float* __restrict__ h, int inStride,
                                                 const float* __restrict__ W,
                                                 unsigned short* __restrict__ outb,
                                                 int n) {
    __shared__ float As[64 * A_PITCH];
    __shared__ float Ws[64 * HID];
    int tid = threadIdx.x;
    int rg = tid >> 4;
    int cgrp = tid & 15;
    int c0 = cgrp * 4;
    int row0 = blockIdx.x * 64;
    if (row0 >= n) return;

    float acc[4][4] = {{0.f}};

    for (int kb = 0; kb < K; kb += 64) {
        for (int i = tid; i < 64 * 16; i += 256) {
            int r = i >> 4;
            int c4 = (i & 15) * 4;
            int grow = row0 + r;
            if (grow >= n) grow = n - 1;
            float4 v = *(const float4*)(h + (long)grow * inStride + kb + c4);
            *(float4*)(As + r * A_PITCH + c4) = v;
        }
        for (int i = tid; i < 64 * 16; i += 256) {
            int k = i >> 4;
            int c4 = (i & 15) * 4;
            *(float4*)(Ws + k * HID + c4) = *(const float4*)(W + (long)(kb + k) * HID + c4);
        }
        __syncthreads();
#pragma unroll 4
        for (int k = 0; k < 64; k += 4) {
            float4 w0 = *(const float4*)(Ws + (k + 0) * HID + c0);
            float4 w1 = *(const float4*)(Ws + (k + 1) * HID + c0);
            float4 w2 = *(const float4*)(Ws + (k + 2) * HID + c0);
            float4 w3 = *(const float4*)(Ws + (k + 3) * HID + c0);
#pragma unroll
            for (int r = 0; r < 4; ++r) {
                float4 a = *(const float4*)(As + (rg * 4 + r) * A_PITCH + k);
                acc[r][0] += a.x * w0.x + a.y * w1.x + a.z * w2.x + a.w * w3.x;
                acc[r][1] += a.x * w0.y + a.y * w1.y + a.z * w2.y + a.w * w3.y;
                acc[r][2] += a.x * w0.z + a.y * w1.z + a.z * w2.z + a.w * w3.z;
                acc[r][3] += a.x * w0.w + a.y * w1.w + a.z * w2.w + a.w * w3.w;
            }
        }
        __syncthreads();
    }
#pragma unroll
    for (int r = 0; r < 4; ++r) {
        int grow = row0 + rg * 4 + r;
        if (grow < n) {
            ushort4 o;
            o.x = f2b(acc[r][0]);
            o.y = f2b(acc[r][1]);
            o.z = f2b(acc[r][2]);
            o.w = f2b(acc[r][3]);
            *(ushort4*)(outb + (long)grow * HID + c0) = o;
        }
    }
}

// ---------------------------------------------------------------------------
// Exact CSR build: histogram of dst, 3-pass exclusive scan, 50k-cursor fill.
// Record = src(16b) | bf16(weight)<<16 -> 4B; ecsr = 3.2 MB, L2-resident,
// so re-dirtied lines coalesce in cache instead of round-tripping to HBM.
// ---------------------------------------------------------------------------
__global__ __launch_bounds__(256) void hist_dst(const int* __restrict__ dst,
                                                int* __restrict__ deg, int E) {
    int e = blockIdx.x * 256 + threadIdx.x;
    if (e < E) atomicAdd(&deg[dst[e]], 1);
}

__global__ __launch_bounds__(256) void scan_a(const int* __restrict__ deg,
                                              int* __restrict__ off,
                                              int* __restrict__ bsum, int n) {
    __shared__ int tmp[256];
    int i = blockIdx.x * 256 + threadIdx.x;
    int v = (i < n) ? deg[i] : 0;
    tmp[threadIdx.x] = v;
    __syncthreads();
    for (int d = 1; d < 256; d <<= 1) {
        int t = (threadIdx.x >= d) ? tmp[threadIdx.x - d] : 0;
        __syncthreads();
        tmp[threadIdx.x] += t;
        __syncthreads();
    }
    if (i < n) off[i] = tmp[threadIdx.x] - v;
    if (threadIdx.x == 255) bsum[blockIdx.x] = tmp[255];
}

__global__ __launch_bounds__(256) void scan_b(int* __restrict__ bsum, int nblk) {
    __shared__ int tmp[256];
    int v = (threadIdx.x < nblk) ? bsum[threadIdx.x] : 0;
    tmp[threadIdx.x] = v;
    __syncthreads();
    for (int d = 1; d < 256; d <<= 1) {
        int t = (threadIdx.x >= d) ? tmp[threadIdx.x - d] : 0;
        __syncthreads();
        tmp[threadIdx.x] += t;
        __syncthreads();
    }
    if (threadIdx.x < nblk) bsum[threadIdx.x] = tmp[threadIdx.x] - v;
}

__global__ __launch_bounds__(256) void scan_c(int* __restrict__ off,
                                              const int* __restrict__ bsum,
                                              int* __restrict__ pos, int n) {
    int i = blockIdx.x * 256 + threadIdx.x;
    if (i >= n) return;
    int o = off[i] + bsum[blockIdx.x];
    off[i] = o;
    pos[i] = o;
}

__global__ __launch_bounds__(256) void fill_csr(const int* __restrict__ src,
                                                const int* __restrict__ dst,
                                                const float* __restrict__ ew,
                                                int* __restrict__ pos,
                                                unsigned* __restrict__ ecsr, int E) {
    int e = blockIdx.x * 256 + threadIdx.x;
    if (e >= E) return;
    int p = atomicAdd(&pos[dst[e]], 1);
    ecsr[p] = (unsigned)src[e] | ((unsigned)f2b(ew[e]) << 16);
}

// ---------------------------------------------------------------------------
// Aggregate + bias + ReLU. One 16-lane group per node; 4-stream software
// pipeline with metadata prefetched a quartet ahead -> 16 independent
// gathers in flight per wave. lin is bf16: lane reads ushort4 (8B), a
// 16-lane group covers the full 128B row. Output row written f32 into hcat.
// ---------------------------------------------------------------------------
__global__ __launch_bounds__(256) void aggregate(const unsigned short* __restrict__ linb,
                                                 const unsigned* __restrict__ ecsr,
                                                 const int* __restrict__ off,
                                                 const int* __restrict__ deg,
                                                 const float* __restrict__ bias,
                                                 float* __restrict__ hout, int n) {
    int cl = threadIdx.x & 15;
    float4 b4 = *(const float4*)(bias + cl * 4);
    int grp = (blockIdx.x * 256 + threadIdx.x) >> 4;
    int ngrp = (gridDim.x * 256) >> 4;
    for (int node = grp; node < n; node += ngrp) {
        int start = off[node];
        int cnt = deg[node];
        float ax = 0.f, ay = 0.f, az = 0.f, aw = 0.f;

        int s[4];
        float w[4];
#pragma unroll
        for (int t = 0; t < 4; ++t) {
            s[t] = 0; w[t] = 0.f;
            if (t < cnt) {
                unsigned m = ecsr[start + t];
                s[t] = (int)(m & 0xFFFFu);
                w[t] = b2f((unsigned short)(m >> 16));
            }
        }
        for (int bb = 0; bb < cnt; bb += 4) {
            int s2[4];
            float w2[4];
#pragma unroll
            for (int t = 0; t < 4; ++t) {
                int e = bb + 4 + t;
                s2[t] = 0; w2[t] = 0.f;
                if (e < cnt) {
                    unsigned m = ecsr[start + e];
                    s2[t] = (int)(m & 0xFFFFu);
                    w2[t] = b2f((unsigned short)(m >> 16));
                }
            }
            ushort4 u0 = *(const ushort4*)(linb + (long)s[0] * HID + cl * 4);
            ushort4 u1 = *(const ushort4*)(linb + (long)s[1] * HID + cl * 4);
            ushort4 u2 = *(const ushort4*)(linb + (long)s[2] * HID + cl * 4);
            ushort4 u3 = *(const ushort4*)(linb + (long)s[3] * HID + cl * 4);
            ax += b2f(u0.x) * w[0] + b2f(u1.x) * w[1] + b2f(u2.x) * w[2] + b2f(u3.x) * w[3];
            ay += b2f(u0.y) * w[0] + b2f(u1.y) * w[1] + b2f(u2.y) * w[2] + b2f(u3.y) * w[3];
            az += b2f(u0.z) * w[0] + b2f(u1.z) * w[1] + b2f(u2.z) * w[2] + b2f(u3.z) * w[3];
            aw += b2f(u0.w) * w[0] + b2f(u1.w) * w[1] + b2f(u2.w) * w[2] + b2f(u3.w) * w[3];
#pragma unroll
            for (int t = 0; t < 4; ++t) { s[t] = s2[t]; w[t] = w2[t]; }
        }

        float4 o;
        o.x = fmaxf(ax + b4.x, 0.f);
        o.y = fmaxf(ay + b4.y, 0.f);
        o.z = fmaxf(az + b4.z, 0.f);
        o.w = fmaxf(aw + b4.w, 0.f);
        *(float4*)(hout + (long)node * JK_DIM + cl * 4) = o;
    }
}

// ---------------------------------------------------------------------------
// Transpose Wlin[192,40] -> Wt[40,192] (runs once, stays L2-hot).
// ---------------------------------------------------------------------------
__global__ __launch_bounds__(256) void transpose_w(const float* __restrict__ W,
                                                   float* __restrict__ Wt) {
    int i = blockIdx.x * 256 + threadIdx.x;
    if (i < JK_DIM * OUT_DIM) {
        int k = i / OUT_DIM;
        int c = i - k * OUT_DIM;
        Wt[c * JK_DIM + k] = W[i];
    }
}

// ---------------------------------------------------------------------------
// Final: out[n,40] = hcat[n,192] @ Wlin[192,40] + blin.
// 64-row tile per 256-thread block; thread = 2 rows x 5 cols; Wt in LDS at
// pitch 196; pool reused as epilogue staging for coalesced float4 stores.
// ---------------------------------------------------------------------------
__global__ __launch_bounds__(256) void final_gemm(const float* __restrict__ hcat,
                                                  const float* __restrict__ Wt,
                                                  const float* __restrict__ b,
                                                  float* __restrict__ out, int n) {
    __shared__ float pool[OUT_DIM * W_PITCH];  // 31360 B
    int tid = threadIdx.x;
    for (int i = tid; i < OUT_DIM * 48; i += 256) {
        int c = i / 48;
        int q = (i - c * 48) * 4;
        *(float4*)(pool + c * W_PITCH + q) = *(const float4*)(Wt + (long)c * JK_DIM + q);
    }
    __syncthreads();

    int rg = tid >> 3;
    int cg = tid & 7;
    int c0 = cg * 5;
    int row0 = blockIdx.x * 64;
    int r0 = row0 + rg * 2;
    int ra = r0 < n ? r0 : n - 1;
    int rb = r0 + 1 < n ? r0 + 1 : n - 1;
    const float* ha = hcat + (long)ra * JK_DIM;
    const float* hb = hcat + (long)rb * JK_DIM;

    float acc[2][5];
#pragma unroll
    for (int r = 0; r < 2; ++r)
#pragma unroll
        for (int i = 0; i < 5; ++i) acc[r][i] = 0.f;

#pragma unroll 4
    for (int k = 0; k < JK_DIM; k += 4) {
        float4 va = *(const float4*)(ha + k);
        float4 vb = *(const float4*)(hb + k);
        float4 w0 = *(const float4*)(pool + (c0 + 0) * W_PITCH + k);
        float4 w1 = *(const float4*)(pool + (c0 + 1) * W_PITCH + k);
        float4 w2 = *(const float4*)(pool + (c0 + 2) * W_PITCH + k);
        float4 w3 = *(const float4*)(pool + (c0 + 3) * W_PITCH + k);
        float4 w4 = *(const float4*)(pool + (c0 + 4) * W_PITCH + k);
        acc[0][0] += va.x * w0.x + va.y * w0.y + va.z * w0.z + va.w * w0.w;
        acc[0][1] += va.x * w1.x + va.y * w1.y + va.z * w1.z + va.w * w1.w;
        acc[0][2] += va.x * w2.x + va.y * w2.y + va.z * w2.z + va.w * w2.w;
        acc[0][3] += va.x * w3.x + va.y * w3.y + va.z * w3.z + va.w * w3.w;
        acc[0][4] += va.x * w4.x + va.y * w4.y + va.z * w4.z + va.w * w4.w;
        acc[1][0] += vb.x * w0.x + vb.y * w0.y + vb.z * w0.z + vb.w * w0.w;
        acc[1][1] += vb.x * w1.x + vb.y * w1.y + vb.z * w1.z + vb.w * w1.w;
        acc[1][2] += vb.x * w2.x + vb.y * w2.y + vb.z * w2.z + vb.w * w2.w;
        acc[1][3] += vb.x * w3.x + vb.y * w3.y + vb.z * w3.z + vb.w * w3.w;
        acc[1][4] += vb.x * w4.x + vb.y * w4.y + vb.z * w4.z + vb.w * w4.w;
    }

    __syncthreads();
#pragma unroll
    for (int r = 0; r < 2; ++r)
#pragma unroll
        for (int i = 0; i < 5; ++i)
            pool[(rg * 2 + r) * FG_PITCH + c0 + i] = acc[r][i] + b[c0 + i];
    __syncthreads();

    if (row0 + 64 <= n) {
        for (int i = tid; i < 64 * OUT_DIM / 4; i += 256) {
            int f = i * 4;
            int row = f / OUT_DIM;
            int col = f - row * OUT_DIM;
            *(float4*)(out + (long)(row0 + row) * OUT_DIM + col) =
                *(const float4*)(pool + row * FG_PITCH + col);
        }
    } else {
        for (int i = tid; i < 64 * OUT_DIM; i += 256) {
            int row = i / OUT_DIM;
            int col = i - row * OUT_DIM;
            if (row0 + row < n)
                out[(long)(row0 + row) * OUT_DIM + col] = pool[row * FG_PITCH + col];
        }
    }
}

// ---------------------------------------------------------------------------
extern "C" void kernel_launch(void* const* d_in, const int* in_sizes, int n_in,
                              void* d_out, int out_size, void* d_ws, size_t ws_size,
                              hipStream_t stream) {
    const float* x    = (const float*)d_in[0];
    const int*   ei   = (const int*)d_in[1];
    const float* ew   = (const float*)d_in[2];
    const float* W1   = (const float*)d_in[3];
    const float* b1   = (const float*)d_in[4];
    const float* W2   = (const float*)d_in[5];
    const float* b2   = (const float*)d_in[6];
    const float* W3   = (const float*)d_in[7];
    const float* b3   = (const float*)d_in[8];
    const float* Wlin = (const float*)d_in[9];
    const float* blin = (const float*)d_in[10];
    float* out = (float*)d_out;

    const int N = in_sizes[0] / 128;   // 50000
    const int E = in_sizes[2];         // 800000
    const int* src = ei;
    const int* dst = ei + E;

    // Workspace: linb(bf16) | hcat | deg,off,pos [N] | bsum | Wt | ecsr [E u32]
    char* wsb = (char*)d_ws;
    unsigned short* linb = (unsigned short*)wsb;    wsb += (long)N * HID * 2;
    float* hcat = (float*)wsb;                      wsb += (long)N * JK_DIM * 4;
    int* deg    = (int*)wsb;                        wsb += (long)N * 4;
    int* off    = (int*)wsb;                        wsb += (long)N * 4;
    int* pos    = (int*)wsb;                        wsb += (long)N * 4;
    int* bsum   = (int*)wsb;                        wsb += 256 * 4;
    float* Wt   = (float*)wsb;                      wsb += (long)JK_DIM * OUT_DIM * 4;
    unsigned* ecsr = (unsigned*)wsb;

    dim3 blk(256);
    const int nblkN = (N + 255) / 256;     // 196
    dim3 gN(nblkN);
    dim3 gE((E + 255) / 256);
    dim3 gGemm((N + 63) / 64);
    dim3 gAgg((N + 15) / 16);
    dim3 gFin((N + 63) / 64);

    float* h1 = hcat;           // columns [0,64)   of hcat[N,192]
    float* h2 = hcat + HID;     // columns [64,128)
    float* h3 = hcat + 2 * HID; // columns [128,192)

    // ---- exact CSR build + W transpose (once per launch) ----
    hipMemsetAsync(deg, 0, (long)N * 4, stream);
    hist_dst<<<gE, blk, 0, stream>>>(dst, deg, E);
    scan_a<<<gN, blk, 0, stream>>>(deg, off, bsum, N);
    scan_b<<<1, blk, 0, stream>>>(bsum, nblkN);
    scan_c<<<gN, blk, 0, stream>>>(off, bsum, pos, N);
    fill_csr<<<gE, blk, 0, stream>>>(src, dst, ew, pos, ecsr, E);
    transpose_w<<<(JK_DIM * OUT_DIM + 255) / 256, blk, 0, stream>>>(Wlin, Wt);

    // ---- layer 1 (K=128) ----
    gemm_tile<128><<<gGemm, blk, 0, stream>>>(x, 128, W1, linb, N);
    aggregate<<<gAgg, blk, 0, stream>>>(linb, ecsr, off, deg, b1, h1, N);

    // ---- layer 2 (K=64, reads h1 inside hcat with stride 192) ----
    gemm_tile<64><<<gGemm, blk, 0, stream>>>(h1, JK_DIM, W2, linb, N);
    aggregate<<<gAgg, blk, 0, stream>>>(linb, ecsr, off, deg, b2, h2, N);

    // ---- layer 3 ----
    gemm_tile<64><<<gGemm, blk, 0, stream>>>(h2, JK_DIM, W3, linb, N);
    aggregate<<<gAgg, blk, 0, stream>>>(linb, ecsr, off, deg, b3, h3, N);

    // ---- JK linear ----
    final_gemm<<<gFin, blk, 0, stream>>>(hcat, Wt, blin, out, N);
}

// Round 13
// 326.516 us; speedup vs baseline: 3.7127x; 1.0126x over previous
//
#include <hip/hip_runtime.h>

// Problem constants: N=50000, E=800000, IN=128, HID=64, OUT=40
#define HID 64
#define JK_DIM 192
#define OUT_DIM 40
#define A_PITCH 68     // gemm_tile A-tile pitch: 16B aligned, max 2-way bank alias
#define W_PITCH 196    // final_gemm LDS pitch for Wt rows
#define FG_PITCH 44    // final_gemm epilogue staging pitch

// bf16 helpers (RNE pack; packed-word unpack via shift/mask)
__device__ inline unsigned short f2b(float f) {
    unsigned u = __float_as_uint(f);
    unsigned r = u + 0x7FFF + ((u >> 16) & 1);
    return (unsigned short)(r >> 16);
}
__device__ inline float b2f(unsigned short u) {
    return __uint_as_float(((unsigned)u) << 16);
}
__device__ inline float blo(unsigned u) { return __uint_as_float(u << 16); }
__device__ inline float bhi(unsigned u) { return __uint_as_float(u & 0xFFFF0000u); }

// ---------------------------------------------------------------------------
// Register-tiled GEMM: lin[64x64 tile](bf16) = h[64 x K](f32) @ W[K x 64].
// Block = 256 threads -> 16 row-groups x 16 col-groups, thread = 4x4 tile.
// ---------------------------------------------------------------------------
template <int K>
__global__ __launch_bounds__(256) void gemm_tile(const float* __restrict__ h, int inStride,
                                                 const float* __restrict__ W,
                                                 unsigned short* __restrict__ outb,
                                                 int n) {
    __shared__ float As[64 * A_PITCH];
    __shared__ float Ws[64 * HID];
    int tid = threadIdx.x;
    int rg = tid >> 4;
    int cgrp = tid & 15;
    int c0 = cgrp * 4;
    int row0 = blockIdx.x * 64;
    if (row0 >= n) return;

    float acc[4][4] = {{0.f}};

    for (int kb = 0; kb < K; kb += 64) {
        for (int i = tid; i < 64 * 16; i += 256) {
            int r = i >> 4;
            int c4 = (i & 15) * 4;
            int grow = row0 + r;
            if (grow >= n) grow = n - 1;
            float4 v = *(const float4*)(h + (long)grow * inStride + kb + c4);
            *(float4*)(As + r * A_PITCH + c4) = v;
        }
        for (int i = tid; i < 64 * 16; i += 256) {
            int k = i >> 4;
            int c4 = (i & 15) * 4;
            *(float4*)(Ws + k * HID + c4) = *(const float4*)(W + (long)(kb + k) * HID + c4);
        }
        __syncthreads();
#pragma unroll 4
        for (int k = 0; k < 64; k += 4) {
            float4 w0 = *(const float4*)(Ws + (k + 0) * HID + c0);
            float4 w1 = *(const float4*)(Ws + (k + 1) * HID + c0);
            float4 w2 = *(const float4*)(Ws + (k + 2) * HID + c0);
            float4 w3 = *(const float4*)(Ws + (k + 3) * HID + c0);
#pragma unroll
            for (int r = 0; r < 4; ++r) {
                float4 a = *(const float4*)(As + (rg * 4 + r) * A_PITCH + k);
                acc[r][0] += a.x * w0.x + a.y * w1.x + a.z * w2.x + a.w * w3.x;
                acc[r][1] += a.x * w0.y + a.y * w1.y + a.z * w2.y + a.w * w3.y;
                acc[r][2] += a.x * w0.z + a.y * w1.z + a.z * w2.z + a.w * w3.z;
                acc[r][3] += a.x * w0.w + a.y * w1.w + a.z * w2.w + a.w * w3.w;
            }
        }
        __syncthreads();
    }
#pragma unroll
    for (int r = 0; r < 4; ++r) {
        int grow = row0 + rg * 4 + r;
        if (grow < n) {
            ushort4 o;
            o.x = f2b(acc[r][0]);
            o.y = f2b(acc[r][1]);
            o.z = f2b(acc[r][2]);
            o.w = f2b(acc[r][3]);
            *(ushort4*)(outb + (long)grow * HID + c0) = o;
        }
    }
}

// ---------------------------------------------------------------------------
// XCD-partitioned histogram: partition p = blockIdx&7 (round-robin block->XCD
// heuristic) scans all edges, counts only its own dst range -> deg atomics
// and their dirty lines stay XCD-local.
// ---------------------------------------------------------------------------
__global__ __launch_bounds__(256) void hist_dst(const int* __restrict__ dst,
                                                int* __restrict__ deg, int E, int part) {
    int p = blockIdx.x & 7;
    int bid = blockIdx.x >> 3;
    int nblk = gridDim.x >> 3;
    int lo = p * part, hi = lo + part;
    for (int e = bid * 256 + threadIdx.x; e < E; e += nblk * 256) {
        int d = dst[e];
        if (d >= lo && d < hi) atomicAdd(&deg[d], 1);
    }
}

__global__ __launch_bounds__(256) void scan_a(const int* __restrict__ deg,
                                              int* __restrict__ off,
                                              int* __restrict__ bsum, int n) {
    __shared__ int tmp[256];
    int i = blockIdx.x * 256 + threadIdx.x;
    int v = (i < n) ? deg[i] : 0;
    tmp[threadIdx.x] = v;
    __syncthreads();
    for (int d = 1; d < 256; d <<= 1) {
        int t = (threadIdx.x >= d) ? tmp[threadIdx.x - d] : 0;
        __syncthreads();
        tmp[threadIdx.x] += t;
        __syncthreads();
    }
    if (i < n) off[i] = tmp[threadIdx.x] - v;
    if (threadIdx.x == 255) bsum[blockIdx.x] = tmp[255];
}

__global__ __launch_bounds__(256) void scan_b(int* __restrict__ bsum, int nblk) {
    __shared__ int tmp[256];
    int v = (threadIdx.x < nblk) ? bsum[threadIdx.x] : 0;
    tmp[threadIdx.x] = v;
    __syncthreads();
    for (int d = 1; d < 256; d <<= 1) {
        int t = (threadIdx.x >= d) ? tmp[threadIdx.x - d] : 0;
        __syncthreads();
        tmp[threadIdx.x] += t;
        __syncthreads();
    }
    if (threadIdx.x < nblk) bsum[threadIdx.x] = tmp[threadIdx.x] - v;
}

__global__ __launch_bounds__(256) void scan_c(int* __restrict__ off,
                                              const int* __restrict__ bsum,
                                              int* __restrict__ pos, int n) {
    int i = blockIdx.x * 256 + threadIdx.x;
    if (i >= n) return;
    int o = off[i] + bsum[blockIdx.x];
    off[i] = o;
    pos[i] = o;
}

// ---------------------------------------------------------------------------
// XCD-partitioned CSR fill: partition p handles dst in [p*part,(p+1)*part).
// All ~16 stores to a given ecsr line issue from one XCD, its 400KB active
// window stays resident in that XCD's L2, so lines accumulate and write back
// ONCE (kills the 64B-line-per-store amplification measured in r12).
// Reads of src/dst/ew are L2/L3-hot (9.6MB total) -> 8x re-read is cheap.
// ---------------------------------------------------------------------------
__global__ __launch_bounds__(256) void fill_csr(const int* __restrict__ src,
                                                const int* __restrict__ dst,
                                                const float* __restrict__ ew,
                                                int* __restrict__ pos,
                                                unsigned* __restrict__ ecsr,
                                                int E, int part) {
    int p = blockIdx.x & 7;
    int bid = blockIdx.x >> 3;
    int nblk = gridDim.x >> 3;
    int lo = p * part, hi = lo + part;
    for (int e = bid * 256 + threadIdx.x; e < E; e += nblk * 256) {
        int d = dst[e];
        if (d >= lo && d < hi) {
            int q = atomicAdd(&pos[d], 1);
            ecsr[q] = (unsigned)src[e] | ((unsigned)f2b(ew[e]) << 16);
        }
    }
}

// ---------------------------------------------------------------------------
// Aggregate + bias + ReLU. One 8-lane group per node (8 nodes/wave); lane
// covers 16B (8 bf16 cols) so one uint4 gather fetches its row slice ->
// half the gather instructions of the 16-lane version. 4-stream software
// pipeline keeps 32 independent gathers in flight per wave. bf16 unpack is
// shift/mask. Output row written f32 into a column block of hcat.
// ---------------------------------------------------------------------------
__global__ __launch_bounds__(256) void aggregate(const unsigned short* __restrict__ linb,
                                                 const unsigned* __restrict__ ecsr,
                                                 const int* __restrict__ off,
                                                 const int* __restrict__ deg,
                                                 const float* __restrict__ bias,
                                                 float* __restrict__ hout, int n) {
    int cl = threadIdx.x & 7;       // 16B slice within the 128B bf16 row
    float4 bLo = *(const float4*)(bias + cl * 8);
    float4 bHi = *(const float4*)(bias + cl * 8 + 4);
    int grp = (blockIdx.x * 256 + threadIdx.x) >> 3;
    int ngrp = (gridDim.x * 256) >> 3;
    for (int node = grp; node < n; node += ngrp) {
        int start = off[node];
        int cnt = deg[node];
        float acc[8];
#pragma unroll
        for (int i = 0; i < 8; ++i) acc[i] = 0.f;

        int s[4];
        float w[4];
#pragma unroll
        for (int t = 0; t < 4; ++t) {
            s[t] = 0; w[t] = 0.f;
            if (t < cnt) {
                unsigned m = ecsr[start + t];
                s[t] = (int)(m & 0xFFFFu);
                w[t] = b2f((unsigned short)(m >> 16));
            }
        }
        for (int bb = 0; bb < cnt; bb += 4) {
            int s2[4];
            float w2[4];
#pragma unroll
            for (int t = 0; t < 4; ++t) {
                int e = bb + 4 + t;
                s2[t] = 0; w2[t] = 0.f;
                if (e < cnt) {
                    unsigned m = ecsr[start + e];
                    s2[t] = (int)(m & 0xFFFFu);
                    w2[t] = b2f((unsigned short)(m >> 16));
                }
            }
            uint4 u0 = *(const uint4*)(linb + (long)s[0] * HID + cl * 8);
            uint4 u1 = *(const uint4*)(linb + (long)s[1] * HID + cl * 8);
            uint4 u2 = *(const uint4*)(linb + (long)s[2] * HID + cl * 8);
            uint4 u3 = *(const uint4*)(linb + (long)s[3] * HID + cl * 8);
            acc[0] += blo(u0.x) * w[0] + blo(u1.x) * w[1] + blo(u2.x) * w[2] + blo(u3.x) * w[3];
            acc[1] += bhi(u0.x) * w[0] + bhi(u1.x) * w[1] + bhi(u2.x) * w[2] + bhi(u3.x) * w[3];
            acc[2] += blo(u0.y) * w[0] + blo(u1.y) * w[1] + blo(u2.y) * w[2] + blo(u3.y) * w[3];
            acc[3] += bhi(u0.y) * w[0] + bhi(u1.y) * w[1] + bhi(u2.y) * w[2] + bhi(u3.y) * w[3];
            acc[4] += blo(u0.z) * w[0] + blo(u1.z) * w[1] + blo(u2.z) * w[2] + blo(u3.z) * w[3];
            acc[5] += bhi(u0.z) * w[0] + bhi(u1.z) * w[1] + bhi(u2.z) * w[2] + bhi(u3.z) * w[3];
            acc[6] += blo(u0.w) * w[0] + blo(u1.w) * w[1] + blo(u2.w) * w[2] + blo(u3.w) * w[3];
            acc[7] += bhi(u0.w) * w[0] + bhi(u1.w) * w[1] + bhi(u2.w) * w[2] + bhi(u3.w) * w[3];
#pragma unroll
            for (int t = 0; t < 4; ++t) { s[t] = s2[t]; w[t] = w2[t]; }
        }

        float4 lo4, hi4;
        lo4.x = fmaxf(acc[0] + bLo.x, 0.f);
        lo4.y = fmaxf(acc[1] + bLo.y, 0.f);
        lo4.z = fmaxf(acc[2] + bLo.z, 0.f);
        lo4.w = fmaxf(acc[3] + bLo.w, 0.f);
        hi4.x = fmaxf(acc[4] + bHi.x, 0.f);
        hi4.y = fmaxf(acc[5] + bHi.y, 0.f);
        hi4.z = fmaxf(acc[6] + bHi.z, 0.f);
        hi4.w = fmaxf(acc[7] + bHi.w, 0.f);
        float* o = hout + (long)node * JK_DIM + cl * 8;
        *(float4*)(o) = lo4;
        *(float4*)(o + 4) = hi4;
    }
}

// ---------------------------------------------------------------------------
// Transpose Wlin[192,40] -> Wt[40,192] (runs once, stays L2-hot).
// ---------------------------------------------------------------------------
__global__ __launch_bounds__(256) void transpose_w(const float* __restrict__ W,
                                                   float* __restrict__ Wt) {
    int i = blockIdx.x * 256 + threadIdx.x;
    if (i < JK_DIM * OUT_DIM) {
        int k = i / OUT_DIM;
        int c = i - k * OUT_DIM;
        Wt[c * JK_DIM + k] = W[i];
    }
}

// ---------------------------------------------------------------------------
// Final: out[n,40] = hcat[n,192] @ Wlin[192,40] + blin.
// 64-row tile per 256-thread block; thread = 2 rows x 5 cols; Wt in LDS at
// pitch 196; pool reused as epilogue staging for coalesced float4 stores.
// ---------------------------------------------------------------------------
__global__ __launch_bounds__(256) void final_gemm(const float* __restrict__ hcat,
                                                  const float* __restrict__ Wt,
                                                  const float* __restrict__ b,
                                                  float* __restrict__ out, int n) {
    __shared__ float pool[OUT_DIM * W_PITCH];  // 31360 B
    int tid = threadIdx.x;
    for (int i = tid; i < OUT_DIM * 48; i += 256) {
        int c = i / 48;
        int q = (i - c * 48) * 4;
        *(float4*)(pool + c * W_PITCH + q) = *(const float4*)(Wt + (long)c * JK_DIM + q);
    }
    __syncthreads();

    int rg = tid >> 3;
    int cg = tid & 7;
    int c0 = cg * 5;
    int row0 = blockIdx.x * 64;
    int r0 = row0 + rg * 2;
    int ra = r0 < n ? r0 : n - 1;
    int rb = r0 + 1 < n ? r0 + 1 : n - 1;
    const float* ha = hcat + (long)ra * JK_DIM;
    const float* hb = hcat + (long)rb * JK_DIM;

    float acc[2][5];
#pragma unroll
    for (int r = 0; r < 2; ++r)
#pragma unroll
        for (int i = 0; i < 5; ++i) acc[r][i] = 0.f;

#pragma unroll 4
    for (int k = 0; k < JK_DIM; k += 4) {
        float4 va = *(const float4*)(ha + k);
        float4 vb = *(const float4*)(hb + k);
        float4 w0 = *(const float4*)(pool + (c0 + 0) * W_PITCH + k);
        float4 w1 = *(const float4*)(pool + (c0 + 1) * W_PITCH + k);
        float4 w2 = *(const float4*)(pool + (c0 + 2) * W_PITCH + k);
        float4 w3 = *(const float4*)(pool + (c0 + 3) * W_PITCH + k);
        float4 w4 = *(const float4*)(pool + (c0 + 4) * W_PITCH + k);
        acc[0][0] += va.x * w0.x + va.y * w0.y + va.z * w0.z + va.w * w0.w;
        acc[0][1] += va.x * w1.x + va.y * w1.y + va.z * w1.z + va.w * w1.w;
        acc[0][2] += va.x * w2.x + va.y * w2.y + va.z * w2.z + va.w * w2.w;
        acc[0][3] += va.x * w3.x + va.y * w3.y + va.z * w3.z + va.w * w3.w;
        acc[0][4] += va.x * w4.x + va.y * w4.y + va.z * w4.z + va.w * w4.w;
        acc[1][0] += vb.x * w0.x + vb.y * w0.y + vb.z * w0.z + vb.w * w0.w;
        acc[1][1] += vb.x * w1.x + vb.y * w1.y + vb.z * w1.z + vb.w * w1.w;
        acc[1][2] += vb.x * w2.x + vb.y * w2.y + vb.z * w2.z + vb.w * w2.w;
        acc[1][3] += vb.x * w3.x + vb.y * w3.y + vb.z * w3.z + vb.w * w3.w;
        acc[1][4] += vb.x * w4.x + vb.y * w4.y + vb.z * w4.z + vb.w * w4.w;
    }

    __syncthreads();
#pragma unroll
    for (int r = 0; r < 2; ++r)
#pragma unroll
        for (int i = 0; i < 5; ++i)
            pool[(rg * 2 + r) * FG_PITCH + c0 + i] = acc[r][i] + b[c0 + i];
    __syncthreads();

    if (row0 + 64 <= n) {
        for (int i = tid; i < 64 * OUT_DIM / 4; i += 256) {
            int f = i * 4;
            int row = f / OUT_DIM;
            int col = f - row * OUT_DIM;
            *(float4*)(out + (long)(row0 + row) * OUT_DIM + col) =
                *(const float4*)(pool + row * FG_PITCH + col);
        }
    } else {
        for (int i = tid; i < 64 * OUT_DIM; i += 256) {
            int row = i / OUT_DIM;
            int col = i - row * OUT_DIM;
            if (row0 + row < n)
                out[(long)(row0 + row) * OUT_DIM + col] = pool[row * FG_PITCH + col];
        }
    }
}

// ---------------------------------------------------------------------------
extern "C" void kernel_launch(void* const* d_in, const int* in_sizes, int n_in,
                              void* d_out, int out_size, void* d_ws, size_t ws_size,
                              hipStream_t stream) {
    const float* x    = (const float*)d_in[0];
    const int*   ei   = (const int*)d_in[1];
    const float* ew   = (const float*)d_in[2];
    const float* W1   = (const float*)d_in[3];
    const float* b1   = (const float*)d_in[4];
    const float* W2   = (const float*)d_in[5];
    const float* b2   = (const float*)d_in[6];
    const float* W3   = (const float*)d_in[7];
    const float* b3   = (const float*)d_in[8];
    const float* Wlin = (const float*)d_in[9];
    const float* blin = (const float*)d_in[10];
    float* out = (float*)d_out;

    const int N = in_sizes[0] / 128;   // 50000
    const int E = in_sizes[2];         // 800000
    const int* src = ei;
    const int* dst = ei + E;
    const int PART = (N + 7) / 8;      // 6250 nodes per XCD partition

    // Workspace: linb(bf16) | hcat | deg,off,pos [N] | bsum | Wt | ecsr [E u32]
    char* wsb = (char*)d_ws;
    unsigned short* linb = (unsigned short*)wsb;    wsb += (long)N * HID * 2;
    float* hcat = (float*)wsb;                      wsb += (long)N * JK_DIM * 4;
    int* deg    = (int*)wsb;                        wsb += (long)N * 4;
    int* off    = (int*)wsb;                        wsb += (long)N * 4;
    int* pos    = (int*)wsb;                        wsb += (long)N * 4;
    int* bsum   = (int*)wsb;                        wsb += 256 * 4;
    float* Wt   = (float*)wsb;                      wsb += (long)JK_DIM * OUT_DIM * 4;
    unsigned* ecsr = (unsigned*)wsb;

    dim3 blk(256);
    const int nblkN = (N + 255) / 256;     // 196
    dim3 gN(nblkN);
    dim3 gPart(8 * 104);                   // 8 partitions x 104 blocks
    dim3 gGemm((N + 63) / 64);
    dim3 gAgg((N + 31) / 32);              // 8 nodes per wave
    dim3 gFin((N + 63) / 64);

    float* h1 = hcat;           // columns [0,64)   of hcat[N,192]
    float* h2 = hcat + HID;     // columns [64,128)
    float* h3 = hcat + 2 * HID; // columns [128,192)

    // ---- exact CSR build (XCD-partitioned) + W transpose ----
    hipMemsetAsync(deg, 0, (long)N * 4, stream);
    hist_dst<<<gPart, blk, 0, stream>>>(dst, deg, E, PART);
    scan_a<<<gN, blk, 0, stream>>>(deg, off, bsum, N);
    scan_b<<<1, blk, 0, stream>>>(bsum, nblkN);
    scan_c<<<gN, blk, 0, stream>>>(off, bsum, pos, N);
    fill_csr<<<gPart, blk, 0, stream>>>(src, dst, ew, pos, ecsr, E, PART);
    transpose_w<<<(JK_DIM * OUT_DIM + 255) / 256, blk, 0, stream>>>(Wlin, Wt);

    // ---- layer 1 (K=128) ----
    gemm_tile<128><<<gGemm, blk, 0, stream>>>(x, 128, W1, linb, N);
    aggregate<<<gAgg, blk, 0, stream>>>(linb, ecsr, off, deg, b1, h1, N);

    // ---- layer 2 (K=64, reads h1 inside hcat with stride 192) ----
    gemm_tile<64><<<gGemm, blk, 0, stream>>>(h1, JK_DIM, W2, linb, N);
    aggregate<<<gAgg, blk, 0, stream>>>(linb, ecsr, off, deg, b2, h2, N);

    // ---- layer 3 ----
    gemm_tile<64><<<gGemm, blk, 0, stream>>>(h2, JK_DIM, W3, linb, N);
    aggregate<<<gAgg, blk, 0, stream>>>(linb, ecsr, off, deg, b3, h3, N);

    // ---- JK linear ----
    final_gemm<<<gFin, blk, 0, stream>>>(hcat, Wt, blin, out, N);
}

// Round 14
// 315.728 us; speedup vs baseline: 3.8396x; 1.0342x over previous
//
#include <hip/hip_runtime.h>

// Problem constants: N=50000, E=800000, IN=128, HID=64, OUT=40
#define HID 64
#define JK_DIM 192
#define OUT_DIM 40
#define A_PITCH 68     // gemm A-tile pitch: 16B aligned, max 2-way bank alias
#define W_PITCH 196    // final_gemm LDS pitch for Wt rows
#define FG_PITCH 44    // final_gemm epilogue staging pitch

// bf16 helpers (RNE pack; packed-word unpack via shift/mask)
__device__ inline unsigned short f2b(float f) {
    unsigned u = __float_as_uint(f);
    unsigned r = u + 0x7FFF + ((u >> 16) & 1);
    return (unsigned short)(r >> 16);
}
__device__ inline float b2f(unsigned short u) {
    return __uint_as_float(((unsigned)u) << 16);
}
__device__ inline float blo(unsigned u) { return __uint_as_float(u << 16); }
__device__ inline float bhi(unsigned u) { return __uint_as_float(u & 0xFFFF0000u); }
__device__ inline unsigned pack2(float a, float b) {
    return (unsigned)f2b(a) | ((unsigned)f2b(b) << 16);
}

// ---------------------------------------------------------------------------
// Layer-1 GEMM: lin(bf16) = x[64 x 128](f32) @ W1[128 x 64].
// Block = 256 threads -> 16x16 groups, thread = 4x4 register tile.
// ---------------------------------------------------------------------------
__global__ __launch_bounds__(256) void gemm_f32in(const float* __restrict__ h,
                                                  const float* __restrict__ W,
                                                  unsigned short* __restrict__ outb,
                                                  int n) {
    __shared__ float As[64 * A_PITCH];
    __shared__ float Ws[64 * HID];
    int tid = threadIdx.x;
    int rg = tid >> 4;
    int cgrp = tid & 15;
    int c0 = cgrp * 4;
    int row0 = blockIdx.x * 64;
    if (row0 >= n) return;

    float acc[4][4] = {{0.f}};

    for (int kb = 0; kb < 128; kb += 64) {
        for (int i = tid; i < 64 * 16; i += 256) {
            int r = i >> 4;
            int c4 = (i & 15) * 4;
            int grow = row0 + r;
            if (grow >= n) grow = n - 1;
            float4 v = *(const float4*)(h + (long)grow * 128 + kb + c4);
            *(float4*)(As + r * A_PITCH + c4) = v;
        }
        for (int i = tid; i < 64 * 16; i += 256) {
            int k = i >> 4;
            int c4 = (i & 15) * 4;
            *(float4*)(Ws + k * HID + c4) = *(const float4*)(W + (long)(kb + k) * HID + c4);
        }
        __syncthreads();
#pragma unroll 4
        for (int k = 0; k < 64; k += 4) {
            float4 w0 = *(const float4*)(Ws + (k + 0) * HID + c0);
            float4 w1 = *(const float4*)(Ws + (k + 1) * HID + c0);
            float4 w2 = *(const float4*)(Ws + (k + 2) * HID + c0);
            float4 w3 = *(const float4*)(Ws + (k + 3) * HID + c0);
#pragma unroll
            for (int r = 0; r < 4; ++r) {
                float4 a = *(const float4*)(As + (rg * 4 + r) * A_PITCH + k);
                acc[r][0] += a.x * w0.x + a.y * w1.x + a.z * w2.x + a.w * w3.x;
                acc[r][1] += a.x * w0.y + a.y * w1.y + a.z * w2.y + a.w * w3.y;
                acc[r][2] += a.x * w0.z + a.y * w1.z + a.z * w2.z + a.w * w3.z;
                acc[r][3] += a.x * w0.w + a.y * w1.w + a.z * w2.w + a.w * w3.w;
            }
        }
        __syncthreads();
    }
#pragma unroll
    for (int r = 0; r < 4; ++r) {
        int grow = row0 + rg * 4 + r;
        if (grow < n) {
            ushort4 o;
            o.x = f2b(acc[r][0]);
            o.y = f2b(acc[r][1]);
            o.z = f2b(acc[r][2]);
            o.w = f2b(acc[r][3]);
            *(ushort4*)(outb + (long)grow * HID + c0) = o;
        }
    }
}

// ---------------------------------------------------------------------------
// Layers 2/3 GEMM: lin(bf16) = h[64 x 64](bf16, row stride JK_DIM) @ W[64x64].
// bf16 rows staged+unpacked into f32 LDS tile (uint4 = 8 bf16 per load).
// ---------------------------------------------------------------------------
__global__ __launch_bounds__(256) void gemm_b16in(const unsigned short* __restrict__ h,
                                                  const float* __restrict__ W,
                                                  unsigned short* __restrict__ outb,
                                                  int n) {
    __shared__ float As[64 * A_PITCH];
    __shared__ float Ws[64 * HID];
    int tid = threadIdx.x;
    int rg = tid >> 4;
    int cgrp = tid & 15;
    int c0 = cgrp * 4;
    int row0 = blockIdx.x * 64;
    if (row0 >= n) return;

    // stage A: 64 rows x 64 bf16 (one uint4 = 8 cols per load slot)
    for (int i = tid; i < 64 * 8; i += 256) {
        int r = i >> 3;
        int q = (i & 7) * 8;
        int grow = row0 + r;
        if (grow >= n) grow = n - 1;
        uint4 u = *(const uint4*)(h + (long)grow * JK_DIM + q);
        float4 lo4 = make_float4(blo(u.x), bhi(u.x), blo(u.y), bhi(u.y));
        float4 hi4 = make_float4(blo(u.z), bhi(u.z), blo(u.w), bhi(u.w));
        *(float4*)(As + r * A_PITCH + q) = lo4;
        *(float4*)(As + r * A_PITCH + q + 4) = hi4;
    }
    for (int i = tid; i < 64 * 16; i += 256) {
        int k = i >> 4;
        int c4 = (i & 15) * 4;
        *(float4*)(Ws + k * HID + c4) = *(const float4*)(W + (long)k * HID + c4);
    }
    __syncthreads();

    float acc[4][4] = {{0.f}};
#pragma unroll 4
    for (int k = 0; k < 64; k += 4) {
        float4 w0 = *(const float4*)(Ws + (k + 0) * HID + c0);
        float4 w1 = *(const float4*)(Ws + (k + 1) * HID + c0);
        float4 w2 = *(const float4*)(Ws + (k + 2) * HID + c0);
        float4 w3 = *(const float4*)(Ws + (k + 3) * HID + c0);
#pragma unroll
        for (int r = 0; r < 4; ++r) {
            float4 a = *(const float4*)(As + (rg * 4 + r) * A_PITCH + k);
            acc[r][0] += a.x * w0.x + a.y * w1.x + a.z * w2.x + a.w * w3.x;
            acc[r][1] += a.x * w0.y + a.y * w1.y + a.z * w2.y + a.w * w3.y;
            acc[r][2] += a.x * w0.z + a.y * w1.z + a.z * w2.z + a.w * w3.z;
            acc[r][3] += a.x * w0.w + a.y * w1.w + a.z * w2.w + a.w * w3.w;
        }
    }
#pragma unroll
    for (int r = 0; r < 4; ++r) {
        int grow = row0 + rg * 4 + r;
        if (grow < n) {
            ushort4 o;
            o.x = f2b(acc[r][0]);
            o.y = f2b(acc[r][1]);
            o.z = f2b(acc[r][2]);
            o.w = f2b(acc[r][3]);
            *(ushort4*)(outb + (long)grow * HID + c0) = o;
        }
    }
}

// ---------------------------------------------------------------------------
// XCD-partitioned histogram: partition p = blockIdx&7 counts only its dst
// range so the deg atomics stay XCD-local.
// ---------------------------------------------------------------------------
__global__ __launch_bounds__(256) void hist_dst(const int* __restrict__ dst,
                                                int* __restrict__ deg, int E, int part) {
    int p = blockIdx.x & 7;
    int bid = blockIdx.x >> 3;
    int nblk = gridDim.x >> 3;
    int lo = p * part, hi = lo + part;
    for (int e = bid * 256 + threadIdx.x; e < E; e += nblk * 256) {
        int d = dst[e];
        if (d >= lo && d < hi) atomicAdd(&deg[d], 1);
    }
}

__global__ __launch_bounds__(256) void scan_a(const int* __restrict__ deg,
                                              int* __restrict__ off,
                                              int* __restrict__ bsum, int n) {
    __shared__ int tmp[256];
    int i = blockIdx.x * 256 + threadIdx.x;
    int v = (i < n) ? deg[i] : 0;
    tmp[threadIdx.x] = v;
    __syncthreads();
    for (int d = 1; d < 256; d <<= 1) {
        int t = (threadIdx.x >= d) ? tmp[threadIdx.x - d] : 0;
        __syncthreads();
        tmp[threadIdx.x] += t;
        __syncthreads();
    }
    if (i < n) off[i] = tmp[threadIdx.x] - v;
    if (threadIdx.x == 255) bsum[blockIdx.x] = tmp[255];
}

__global__ __launch_bounds__(256) void scan_b(int* __restrict__ bsum, int nblk) {
    __shared__ int tmp[256];
    int v = (threadIdx.x < nblk) ? bsum[threadIdx.x] : 0;
    tmp[threadIdx.x] = v;
    __syncthreads();
    for (int d = 1; d < 256; d <<= 1) {
        int t = (threadIdx.x >= d) ? tmp[threadIdx.x - d] : 0;
        __syncthreads();
        tmp[threadIdx.x] += t;
        __syncthreads();
    }
    if (threadIdx.x < nblk) bsum[threadIdx.x] = tmp[threadIdx.x] - v;
}

__global__ __launch_bounds__(256) void scan_c(int* __restrict__ off,
                                              const int* __restrict__ bsum,
                                              int* __restrict__ pos, int n) {
    int i = blockIdx.x * 256 + threadIdx.x;
    if (i >= n) return;
    int o = off[i] + bsum[blockIdx.x];
    off[i] = o;
    pos[i] = o;
}

// ---------------------------------------------------------------------------
// XCD-partitioned CSR fill: record = src(16b) | bf16(weight)<<16.
// Partition p's stores stay in its own L2's 400KB window.
// ---------------------------------------------------------------------------
__global__ __launch_bounds__(256) void fill_csr(const int* __restrict__ src,
                                                const int* __restrict__ dst,
                                                const float* __restrict__ ew,
                                                int* __restrict__ pos,
                                                unsigned* __restrict__ ecsr,
                                                int E, int part) {
    int p = blockIdx.x & 7;
    int bid = blockIdx.x >> 3;
    int nblk = gridDim.x >> 3;
    int lo = p * part, hi = lo + part;
    for (int e = bid * 256 + threadIdx.x; e < E; e += nblk * 256) {
        int d = dst[e];
        if (d >= lo && d < hi) {
            int q = atomicAdd(&pos[d], 1);
            ecsr[q] = (unsigned)src[e] | ((unsigned)f2b(ew[e]) << 16);
        }
    }
}

// ---------------------------------------------------------------------------
// Aggregate + bias + ReLU. One 8-lane group per node (8 nodes/wave); lane
// covers 16B (8 bf16 cols) -> one uint4 gather per edge per lane. 8-stream
// software pipeline: 64 independent gathers in flight per wave. Output row
// written bf16 (uint4 = 8 cols) into a column block of hcat.
// ---------------------------------------------------------------------------
__global__ __launch_bounds__(256) void aggregate(const unsigned short* __restrict__ linb,
                                                 const unsigned* __restrict__ ecsr,
                                                 const int* __restrict__ off,
                                                 const int* __restrict__ deg,
                                                 const float* __restrict__ bias,
                                                 unsigned short* __restrict__ hout, int n) {
    int cl = threadIdx.x & 7;       // 16B slice within the 128B bf16 row
    float4 bLo = *(const float4*)(bias + cl * 8);
    float4 bHi = *(const float4*)(bias + cl * 8 + 4);
    int grp = (blockIdx.x * 256 + threadIdx.x) >> 3;
    int ngrp = (gridDim.x * 256) >> 3;
    for (int node = grp; node < n; node += ngrp) {
        int start = off[node];
        int cnt = deg[node];
        float acc[8];
#pragma unroll
        for (int i = 0; i < 8; ++i) acc[i] = 0.f;

        int s[8];
        float w[8];
#pragma unroll
        for (int t = 0; t < 8; ++t) {
            s[t] = 0; w[t] = 0.f;
            if (t < cnt) {
                unsigned m = ecsr[start + t];
                s[t] = (int)(m & 0xFFFFu);
                w[t] = b2f((unsigned short)(m >> 16));
            }
        }
        for (int bb = 0; bb < cnt; bb += 8) {
            int s2[8];
            float w2[8];
#pragma unroll
            for (int t = 0; t < 8; ++t) {
                int e = bb + 8 + t;
                s2[t] = 0; w2[t] = 0.f;
                if (e < cnt) {
                    unsigned m = ecsr[start + e];
                    s2[t] = (int)(m & 0xFFFFu);
                    w2[t] = b2f((unsigned short)(m >> 16));
                }
            }
            uint4 u[8];
#pragma unroll
            for (int t = 0; t < 8; ++t)
                u[t] = *(const uint4*)(linb + (long)s[t] * HID + cl * 8);
#pragma unroll
            for (int t = 0; t < 8; ++t) {
                acc[0] += blo(u[t].x) * w[t];
                acc[1] += bhi(u[t].x) * w[t];
                acc[2] += blo(u[t].y) * w[t];
                acc[3] += bhi(u[t].y) * w[t];
                acc[4] += blo(u[t].z) * w[t];
                acc[5] += bhi(u[t].z) * w[t];
                acc[6] += blo(u[t].w) * w[t];
                acc[7] += bhi(u[t].w) * w[t];
            }
#pragma unroll
            for (int t = 0; t < 8; ++t) { s[t] = s2[t]; w[t] = w2[t]; }
        }

        uint4 o;
        o.x = pack2(fmaxf(acc[0] + bLo.x, 0.f), fmaxf(acc[1] + bLo.y, 0.f));
        o.y = pack2(fmaxf(acc[2] + bLo.z, 0.f), fmaxf(acc[3] + bLo.w, 0.f));
        o.z = pack2(fmaxf(acc[4] + bHi.x, 0.f), fmaxf(acc[5] + bHi.y, 0.f));
        o.w = pack2(fmaxf(acc[6] + bHi.z, 0.f), fmaxf(acc[7] + bHi.w, 0.f));
        *(uint4*)(hout + (long)node * JK_DIM + cl * 8) = o;
    }
}

// ---------------------------------------------------------------------------
// Transpose Wlin[192,40] -> Wt[40,192] (runs once, stays L2-hot).
// ---------------------------------------------------------------------------
__global__ __launch_bounds__(256) void transpose_w(const float* __restrict__ W,
                                                   float* __restrict__ Wt) {
    int i = blockIdx.x * 256 + threadIdx.x;
    if (i < JK_DIM * OUT_DIM) {
        int k = i / OUT_DIM;
        int c = i - k * OUT_DIM;
        Wt[c * JK_DIM + k] = W[i];
    }
}

// ---------------------------------------------------------------------------
// Final: out[n,40](f32) = hcat[n,192](bf16) @ Wlin[192,40] + blin.
// 64-row tile per 256-thread block; thread = 2 rows x 5 cols; Wt in LDS at
// pitch 196; pool reused as epilogue staging for coalesced float4 stores.
// ---------------------------------------------------------------------------
__global__ __launch_bounds__(256) void final_gemm(const unsigned short* __restrict__ hcat,
                                                  const float* __restrict__ Wt,
                                                  const float* __restrict__ b,
                                                  float* __restrict__ out, int n) {
    __shared__ float pool[OUT_DIM * W_PITCH];  // 31360 B
    int tid = threadIdx.x;
    for (int i = tid; i < OUT_DIM * 48; i += 256) {
        int c = i / 48;
        int q = (i - c * 48) * 4;
        *(float4*)(pool + c * W_PITCH + q) = *(const float4*)(Wt + (long)c * JK_DIM + q);
    }
    __syncthreads();

    int rg = tid >> 3;
    int cg = tid & 7;
    int c0 = cg * 5;
    int row0 = blockIdx.x * 64;
    int r0 = row0 + rg * 2;
    int ra = r0 < n ? r0 : n - 1;
    int rb = r0 + 1 < n ? r0 + 1 : n - 1;
    const unsigned short* ha = hcat + (long)ra * JK_DIM;
    const unsigned short* hb = hcat + (long)rb * JK_DIM;

    float acc[2][5];
#pragma unroll
    for (int r = 0; r < 2; ++r)
#pragma unroll
        for (int i = 0; i < 5; ++i) acc[r][i] = 0.f;

#pragma unroll 4
    for (int k = 0; k < JK_DIM; k += 4) {
        uint2 ua = *(const uint2*)(ha + k);
        uint2 ub = *(const uint2*)(hb + k);
        float4 va = make_float4(blo(ua.x), bhi(ua.x), blo(ua.y), bhi(ua.y));
        float4 vb = make_float4(blo(ub.x), bhi(ub.x), blo(ub.y), bhi(ub.y));
        float4 w0 = *(const float4*)(pool + (c0 + 0) * W_PITCH + k);
        float4 w1 = *(const float4*)(pool + (c0 + 1) * W_PITCH + k);
        float4 w2 = *(const float4*)(pool + (c0 + 2) * W_PITCH + k);
        float4 w3 = *(const float4*)(pool + (c0 + 3) * W_PITCH + k);
        float4 w4 = *(const float4*)(pool + (c0 + 4) * W_PITCH + k);
        acc[0][0] += va.x * w0.x + va.y * w0.y + va.z * w0.z + va.w * w0.w;
        acc[0][1] += va.x * w1.x + va.y * w1.y + va.z * w1.z + va.w * w1.w;
        acc[0][2] += va.x * w2.x + va.y * w2.y + va.z * w2.z + va.w * w2.w;
        acc[0][3] += va.x * w3.x + va.y * w3.y + va.z * w3.z + va.w * w3.w;
        acc[0][4] += va.x * w4.x + va.y * w4.y + va.z * w4.z + va.w * w4.w;
        acc[1][0] += vb.x * w0.x + vb.y * w0.y + vb.z * w0.z + vb.w * w0.w;
        acc[1][1] += vb.x * w1.x + vb.y * w1.y + vb.z * w1.z + vb.w * w1.w;
        acc[1][2] += vb.x * w2.x + vb.y * w2.y + vb.z * w2.z + vb.w * w2.w;
        acc[1][3] += vb.x * w3.x + vb.y * w3.y + vb.z * w3.z + vb.w * w3.w;
        acc[1][4] += vb.x * w4.x + vb.y * w4.y + vb.z * w4.z + vb.w * w4.w;
    }

    __syncthreads();
#pragma unroll
    for (int r = 0; r < 2; ++r)
#pragma unroll
        for (int i = 0; i < 5; ++i)
            pool[(rg * 2 + r) * FG_PITCH + c0 + i] = acc[r][i] + b[c0 + i];
    __syncthreads();

    if (row0 + 64 <= n) {
        for (int i = tid; i < 64 * OUT_DIM / 4; i += 256) {
            int f = i * 4;
            int row = f / OUT_DIM;
            int col = f - row * OUT_DIM;
            *(float4*)(out + (long)(row0 + row) * OUT_DIM + col) =
                *(const float4*)(pool + row * FG_PITCH + col);
        }
    } else {
        for (int i = tid; i < 64 * OUT_DIM; i += 256) {
            int row = i / OUT_DIM;
            int col = i - row * OUT_DIM;
            if (row0 + row < n)
                out[(long)(row0 + row) * OUT_DIM + col] = pool[row * FG_PITCH + col];
        }
    }
}

// ---------------------------------------------------------------------------
extern "C" void kernel_launch(void* const* d_in, const int* in_sizes, int n_in,
                              void* d_out, int out_size, void* d_ws, size_t ws_size,
                              hipStream_t stream) {
    const float* x    = (const float*)d_in[0];
    const int*   ei   = (const int*)d_in[1];
    const float* ew   = (const float*)d_in[2];
    const float* W1   = (const float*)d_in[3];
    const float* b1   = (const float*)d_in[4];
    const float* W2   = (const float*)d_in[5];
    const float* b2   = (const float*)d_in[6];
    const float* W3   = (const float*)d_in[7];
    const float* b3   = (const float*)d_in[8];
    const float* Wlin = (const float*)d_in[9];
    const float* blin = (const float*)d_in[10];
    float* out = (float*)d_out;

    const int N = in_sizes[0] / 128;   // 50000
    const int E = in_sizes[2];         // 800000
    const int* src = ei;
    const int* dst = ei + E;
    const int PART = (N + 7) / 8;      // 6250 nodes per XCD partition

    // Workspace: linb(bf16) | hcatb(bf16) | deg,off,pos [N] | bsum | Wt | ecsr
    char* wsb = (char*)d_ws;
    unsigned short* linb  = (unsigned short*)wsb;   wsb += (long)N * HID * 2;
    unsigned short* hcatb = (unsigned short*)wsb;   wsb += (long)N * JK_DIM * 2;
    int* deg    = (int*)wsb;                        wsb += (long)N * 4;
    int* off    = (int*)wsb;                        wsb += (long)N * 4;
    int* pos    = (int*)wsb;                        wsb += (long)N * 4;
    int* bsum   = (int*)wsb;                        wsb += 256 * 4;
    float* Wt   = (float*)wsb;                      wsb += (long)JK_DIM * OUT_DIM * 4;
    unsigned* ecsr = (unsigned*)wsb;

    dim3 blk(256);
    const int nblkN = (N + 255) / 256;     // 196
    dim3 gN(nblkN);
    dim3 gPart(8 * 104);                   // 8 partitions x 104 blocks
    dim3 gGemm((N + 63) / 64);
    dim3 gAgg((N + 31) / 32);              // 8 nodes per wave
    dim3 gFin((N + 63) / 64);

    unsigned short* h1 = hcatb;            // columns [0,64)   of hcat[N,192]
    unsigned short* h2 = hcatb + HID;      // columns [64,128)
    unsigned short* h3 = hcatb + 2 * HID;  // columns [128,192)

    // ---- exact CSR build (XCD-partitioned) + W transpose ----
    hipMemsetAsync(deg, 0, (long)N * 4, stream);
    hist_dst<<<gPart, blk, 0, stream>>>(dst, deg, E, PART);
    scan_a<<<gN, blk, 0, stream>>>(deg, off, bsum, N);
    scan_b<<<1, blk, 0, stream>>>(bsum, nblkN);
    scan_c<<<gN, blk, 0, stream>>>(off, bsum, pos, N);
    fill_csr<<<gPart, blk, 0, stream>>>(src, dst, ew, pos, ecsr, E, PART);
    transpose_w<<<(JK_DIM * OUT_DIM + 255) / 256, blk, 0, stream>>>(Wlin, Wt);

    // ---- layer 1 (K=128, f32 input) ----
    gemm_f32in<<<gGemm, blk, 0, stream>>>(x, W1, linb, N);
    aggregate<<<gAgg, blk, 0, stream>>>(linb, ecsr, off, deg, b1, h1, N);

    // ---- layer 2 (K=64, bf16 input from hcat col block) ----
    gemm_b16in<<<gGemm, blk, 0, stream>>>(h1, W2, linb, N);
    aggregate<<<gAgg, blk, 0, stream>>>(linb, ecsr, off, deg, b2, h2, N);

    // ---- layer 3 ----
    gemm_b16in<<<gGemm, blk, 0, stream>>>(h2, W3, linb, N);
    aggregate<<<gAgg, blk, 0, stream>>>(linb, ecsr, off, deg, b3, h3, N);

    // ---- JK linear ----
    final_gemm<<<gFin, blk, 0, stream>>>(hcatb, Wt, blin, out, N);
}

// Round 15
// 300.162 us; speedup vs baseline: 4.0387x; 1.0519x over previous
//
#include <hip/hip_runtime.h>

// Problem constants: N=50000, E=800000, IN=128, HID=64, OUT=40
#define HID 64
#define JK_DIM 192
#define OUT_DIM 40
#define A_PITCH 68     // gemm A-tile pitch: 16B aligned, max 2-way bank alias
#define W_PITCH 196    // final_gemm LDS pitch for Wt rows
#define FG_PITCH 44    // final_gemm epilogue staging pitch

// bf16 helpers (RNE pack; packed-word unpack via shift/mask)
__device__ inline unsigned short f2b(float f) {
    unsigned u = __float_as_uint(f);
    unsigned r = u + 0x7FFF + ((u >> 16) & 1);
    return (unsigned short)(r >> 16);
}
__device__ inline float b2f(unsigned short u) {
    return __uint_as_float(((unsigned)u) << 16);
}
__device__ inline float blo(unsigned u) { return __uint_as_float(u << 16); }
__device__ inline float bhi(unsigned u) { return __uint_as_float(u & 0xFFFF0000u); }
__device__ inline unsigned pack2(float a, float b) {
    return (unsigned)f2b(a) | ((unsigned)f2b(b) << 16);
}

// ---------------------------------------------------------------------------
// prep: zero deg + transpose Wlin[192,40] -> Wt[40,192] in one launch.
// ---------------------------------------------------------------------------
__global__ __launch_bounds__(256) void prep(int* __restrict__ deg, int n,
                                            const float* __restrict__ W,
                                            float* __restrict__ Wt) {
    int i = blockIdx.x * 256 + threadIdx.x;
    if (i < n) deg[i] = 0;
    if (i < JK_DIM * OUT_DIM) {
        int k = i / OUT_DIM;
        int c = i - k * OUT_DIM;
        Wt[c * JK_DIM + k] = W[i];
    }
}

// ---------------------------------------------------------------------------
// XCD-partitioned histogram, int4-vectorized scan of dst (4 edges/load).
// ---------------------------------------------------------------------------
__global__ __launch_bounds__(256) void hist_dst(const int* __restrict__ dst,
                                                int* __restrict__ deg, int E, int part) {
    int p = blockIdx.x & 7;
    int bid = blockIdx.x >> 3;
    int nblk = gridDim.x >> 3;
    int lo = p * part, hi = lo + part;
    int E4 = E >> 2;
    for (int q = bid * 256 + threadIdx.x; q < E4; q += nblk * 256) {
        int4 d4 = ((const int4*)dst)[q];
        if (d4.x >= lo && d4.x < hi) atomicAdd(&deg[d4.x], 1);
        if (d4.y >= lo && d4.y < hi) atomicAdd(&deg[d4.y], 1);
        if (d4.z >= lo && d4.z < hi) atomicAdd(&deg[d4.z], 1);
        if (d4.w >= lo && d4.w < hi) atomicAdd(&deg[d4.w], 1);
    }
    if (bid == 0 && threadIdx.x < (E & 3)) {
        int e = (E & ~3) + threadIdx.x;
        int d = dst[e];
        if (d >= lo && d < hi) atomicAdd(&deg[d], 1);
    }
}

__global__ __launch_bounds__(256) void scan_a(const int* __restrict__ deg,
                                              int* __restrict__ off,
                                              int* __restrict__ bsum, int n) {
    __shared__ int tmp[256];
    int i = blockIdx.x * 256 + threadIdx.x;
    int v = (i < n) ? deg[i] : 0;
    tmp[threadIdx.x] = v;
    __syncthreads();
    for (int d = 1; d < 256; d <<= 1) {
        int t = (threadIdx.x >= d) ? tmp[threadIdx.x - d] : 0;
        __syncthreads();
        tmp[threadIdx.x] += t;
        __syncthreads();
    }
    if (i < n) off[i] = tmp[threadIdx.x] - v;
    if (threadIdx.x == 255) bsum[blockIdx.x] = tmp[255];
}

__global__ __launch_bounds__(256) void scan_b(int* __restrict__ bsum, int nblk) {
    __shared__ int tmp[256];
    int v = (threadIdx.x < nblk) ? bsum[threadIdx.x] : 0;
    tmp[threadIdx.x] = v;
    __syncthreads();
    for (int d = 1; d < 256; d <<= 1) {
        int t = (threadIdx.x >= d) ? tmp[threadIdx.x - d] : 0;
        __syncthreads();
        tmp[threadIdx.x] += t;
        __syncthreads();
    }
    if (threadIdx.x < nblk) bsum[threadIdx.x] = tmp[threadIdx.x] - v;
}

__global__ __launch_bounds__(256) void scan_c(int* __restrict__ off,
                                              const int* __restrict__ bsum,
                                              int* __restrict__ pos, int n) {
    int i = blockIdx.x * 256 + threadIdx.x;
    if (i >= n) return;
    int o = off[i] + bsum[blockIdx.x];
    off[i] = o;
    pos[i] = o;
}

// ---------------------------------------------------------------------------
// FUSED: XCD-partitioned CSR fill + layer-1 GEMM.
// blockIdx%3 in {0,1} -> fill work (1600 blocks = 8 partitions x 200);
// blockIdx%3 == 2    -> one 64-row GEMM tile (800 slots, 782 used).
// Interleaved mapping co-schedules both kinds across CUs so the
// latency-bound fill hides under the compute-bound GEMM.
// ---------------------------------------------------------------------------
__global__ __launch_bounds__(256) void fill_and_gemm(
        const int* __restrict__ src, const int* __restrict__ dst,
        const float* __restrict__ ew, int* __restrict__ pos,
        unsigned* __restrict__ ecsr, int E, int part,
        const float* __restrict__ x, const float* __restrict__ W1,
        unsigned short* __restrict__ linb, int n) {
    __shared__ float As[64 * A_PITCH];
    __shared__ float Ws[64 * HID];
    int m = blockIdx.x % 3;
    if (m < 2) {
        // ---- fill branch ----
        int f = (blockIdx.x / 3) * 2 + m;          // 0..(2/3*grid)
        int p = f & 7;
        int bid = f >> 3;
        int nblk = ((gridDim.x / 3) * 2) >> 3;
        int lo = p * part, hi = lo + part;
        int E4 = E >> 2;
        for (int q = bid * 256 + threadIdx.x; q < E4; q += nblk * 256) {
            int4 d4 = ((const int4*)dst)[q];
            int e = q * 4;
            if (d4.x >= lo && d4.x < hi) {
                int sl = atomicAdd(&pos[d4.x], 1);
                ecsr[sl] = (unsigned)src[e] | ((unsigned)f2b(ew[e]) << 16);
            }
            if (d4.y >= lo && d4.y < hi) {
                int sl = atomicAdd(&pos[d4.y], 1);
                ecsr[sl] = (unsigned)src[e + 1] | ((unsigned)f2b(ew[e + 1]) << 16);
            }
            if (d4.z >= lo && d4.z < hi) {
                int sl = atomicAdd(&pos[d4.z], 1);
                ecsr[sl] = (unsigned)src[e + 2] | ((unsigned)f2b(ew[e + 2]) << 16);
            }
            if (d4.w >= lo && d4.w < hi) {
                int sl = atomicAdd(&pos[d4.w], 1);
                ecsr[sl] = (unsigned)src[e + 3] | ((unsigned)f2b(ew[e + 3]) << 16);
            }
        }
        if (bid == 0 && threadIdx.x < (E & 3)) {
            int e = (E & ~3) + threadIdx.x;
            int d = dst[e];
            if (d >= lo && d < hi) {
                int sl = atomicAdd(&pos[d], 1);
                ecsr[sl] = (unsigned)src[e] | ((unsigned)f2b(ew[e]) << 16);
            }
        }
        return;
    }
    // ---- gemm branch: lin(bf16) = x[64x128](f32) @ W1[128x64] ----
    int g = blockIdx.x / 3;
    int row0 = g * 64;
    if (row0 >= n) return;
    int tid = threadIdx.x;
    int rg = tid >> 4;
    int cgrp = tid & 15;
    int c0 = cgrp * 4;

    float acc[4][4] = {{0.f}};
    for (int kb = 0; kb < 128; kb += 64) {
        for (int i = tid; i < 64 * 16; i += 256) {
            int r = i >> 4;
            int c4 = (i & 15) * 4;
            int grow = row0 + r;
            if (grow >= n) grow = n - 1;
            float4 v = *(const float4*)(x + (long)grow * 128 + kb + c4);
            *(float4*)(As + r * A_PITCH + c4) = v;
        }
        for (int i = tid; i < 64 * 16; i += 256) {
            int k = i >> 4;
            int c4 = (i & 15) * 4;
            *(float4*)(Ws + k * HID + c4) = *(const float4*)(W1 + (long)(kb + k) * HID + c4);
        }
        __syncthreads();
#pragma unroll 4
        for (int k = 0; k < 64; k += 4) {
            float4 w0 = *(const float4*)(Ws + (k + 0) * HID + c0);
            float4 w1 = *(const float4*)(Ws + (k + 1) * HID + c0);
            float4 w2 = *(const float4*)(Ws + (k + 2) * HID + c0);
            float4 w3 = *(const float4*)(Ws + (k + 3) * HID + c0);
#pragma unroll
            for (int r = 0; r < 4; ++r) {
                float4 a = *(const float4*)(As + (rg * 4 + r) * A_PITCH + k);
                acc[r][0] += a.x * w0.x + a.y * w1.x + a.z * w2.x + a.w * w3.x;
                acc[r][1] += a.x * w0.y + a.y * w1.y + a.z * w2.y + a.w * w3.y;
                acc[r][2] += a.x * w0.z + a.y * w1.z + a.z * w2.z + a.w * w3.z;
                acc[r][3] += a.x * w0.w + a.y * w1.w + a.z * w2.w + a.w * w3.w;
            }
        }
        __syncthreads();
    }
#pragma unroll
    for (int r = 0; r < 4; ++r) {
        int grow = row0 + rg * 4 + r;
        if (grow < n) {
            ushort4 o;
            o.x = f2b(acc[r][0]);
            o.y = f2b(acc[r][1]);
            o.z = f2b(acc[r][2]);
            o.w = f2b(acc[r][3]);
            *(ushort4*)(linb + (long)grow * HID + c0) = o;
        }
    }
}

// ---------------------------------------------------------------------------
// Layers 2/3 GEMM: lin(bf16) = h[64 x 64](bf16, row stride JK_DIM) @ W[64x64].
// ---------------------------------------------------------------------------
__global__ __launch_bounds__(256) void gemm_b16in(const unsigned short* __restrict__ h,
                                                  const float* __restrict__ W,
                                                  unsigned short* __restrict__ outb,
                                                  int n) {
    __shared__ float As[64 * A_PITCH];
    __shared__ float Ws[64 * HID];
    int tid = threadIdx.x;
    int rg = tid >> 4;
    int cgrp = tid & 15;
    int c0 = cgrp * 4;
    int row0 = blockIdx.x * 64;
    if (row0 >= n) return;

    for (int i = tid; i < 64 * 8; i += 256) {
        int r = i >> 3;
        int q = (i & 7) * 8;
        int grow = row0 + r;
        if (grow >= n) grow = n - 1;
        uint4 u = *(const uint4*)(h + (long)grow * JK_DIM + q);
        float4 lo4 = make_float4(blo(u.x), bhi(u.x), blo(u.y), bhi(u.y));
        float4 hi4 = make_float4(blo(u.z), bhi(u.z), blo(u.w), bhi(u.w));
        *(float4*)(As + r * A_PITCH + q) = lo4;
        *(float4*)(As + r * A_PITCH + q + 4) = hi4;
    }
    for (int i = tid; i < 64 * 16; i += 256) {
        int k = i >> 4;
        int c4 = (i & 15) * 4;
        *(float4*)(Ws + k * HID + c4) = *(const float4*)(W + (long)k * HID + c4);
    }
    __syncthreads();

    float acc[4][4] = {{0.f}};
#pragma unroll 4
    for (int k = 0; k < 64; k += 4) {
        float4 w0 = *(const float4*)(Ws + (k + 0) * HID + c0);
        float4 w1 = *(const float4*)(Ws + (k + 1) * HID + c0);
        float4 w2 = *(const float4*)(Ws + (k + 2) * HID + c0);
        float4 w3 = *(const float4*)(Ws + (k + 3) * HID + c0);
#pragma unroll
        for (int r = 0; r < 4; ++r) {
            float4 a = *(const float4*)(As + (rg * 4 + r) * A_PITCH + k);
            acc[r][0] += a.x * w0.x + a.y * w1.x + a.z * w2.x + a.w * w3.x;
            acc[r][1] += a.x * w0.y + a.y * w1.y + a.z * w2.y + a.w * w3.y;
            acc[r][2] += a.x * w0.z + a.y * w1.z + a.z * w2.z + a.w * w3.z;
            acc[r][3] += a.x * w0.w + a.y * w1.w + a.z * w2.w + a.w * w3.w;
        }
    }
#pragma unroll
    for (int r = 0; r < 4; ++r) {
        int grow = row0 + rg * 4 + r;
        if (grow < n) {
            ushort4 o;
            o.x = f2b(acc[r][0]);
            o.y = f2b(acc[r][1]);
            o.z = f2b(acc[r][2]);
            o.w = f2b(acc[r][3]);
            *(ushort4*)(outb + (long)grow * HID + c0) = o;
        }
    }
}

// ---------------------------------------------------------------------------
// Aggregate + bias + ReLU. One 8-lane group per node (8 nodes/wave); lane
// covers 16B (8 bf16 cols). 8-stream software pipeline: 64 independent
// gathers in flight per wave. Output row written bf16 into hcat col block.
// ---------------------------------------------------------------------------
__global__ __launch_bounds__(256) void aggregate(const unsigned short* __restrict__ linb,
                                                 const unsigned* __restrict__ ecsr,
                                                 const int* __restrict__ off,
                                                 const int* __restrict__ deg,
                                                 const float* __restrict__ bias,
                                                 unsigned short* __restrict__ hout, int n) {
    int cl = threadIdx.x & 7;       // 16B slice within the 128B bf16 row
    float4 bLo = *(const float4*)(bias + cl * 8);
    float4 bHi = *(const float4*)(bias + cl * 8 + 4);
    int grp = (blockIdx.x * 256 + threadIdx.x) >> 3;
    int ngrp = (gridDim.x * 256) >> 3;
    for (int node = grp; node < n; node += ngrp) {
        int start = off[node];
        int cnt = deg[node];
        float acc[8];
#pragma unroll
        for (int i = 0; i < 8; ++i) acc[i] = 0.f;

        int s[8];
        float w[8];
#pragma unroll
        for (int t = 0; t < 8; ++t) {
            s[t] = 0; w[t] = 0.f;
            if (t < cnt) {
                unsigned m = ecsr[start + t];
                s[t] = (int)(m & 0xFFFFu);
                w[t] = b2f((unsigned short)(m >> 16));
            }
        }
        for (int bb = 0; bb < cnt; bb += 8) {
            int s2[8];
            float w2[8];
#pragma unroll
            for (int t = 0; t < 8; ++t) {
                int e = bb + 8 + t;
                s2[t] = 0; w2[t] = 0.f;
                if (e < cnt) {
                    unsigned m = ecsr[start + e];
                    s2[t] = (int)(m & 0xFFFFu);
                    w2[t] = b2f((unsigned short)(m >> 16));
                }
            }
            uint4 u[8];
#pragma unroll
            for (int t = 0; t < 8; ++t)
                u[t] = *(const uint4*)(linb + (long)s[t] * HID + cl * 8);
#pragma unroll
            for (int t = 0; t < 8; ++t) {
                acc[0] += blo(u[t].x) * w[t];
                acc[1] += bhi(u[t].x) * w[t];
                acc[2] += blo(u[t].y) * w[t];
                acc[3] += bhi(u[t].y) * w[t];
                acc[4] += blo(u[t].z) * w[t];
                acc[5] += bhi(u[t].z) * w[t];
                acc[6] += blo(u[t].w) * w[t];
                acc[7] += bhi(u[t].w) * w[t];
            }
#pragma unroll
            for (int t = 0; t < 8; ++t) { s[t] = s2[t]; w[t] = w2[t]; }
        }

        uint4 o;
        o.x = pack2(fmaxf(acc[0] + bLo.x, 0.f), fmaxf(acc[1] + bLo.y, 0.f));
        o.y = pack2(fmaxf(acc[2] + bLo.z, 0.f), fmaxf(acc[3] + bLo.w, 0.f));
        o.z = pack2(fmaxf(acc[4] + bHi.x, 0.f), fmaxf(acc[5] + bHi.y, 0.f));
        o.w = pack2(fmaxf(acc[6] + bHi.z, 0.f), fmaxf(acc[7] + bHi.w, 0.f));
        *(uint4*)(hout + (long)node * JK_DIM + cl * 8) = o;
    }
}

// ---------------------------------------------------------------------------
// Final: out[n,40](f32) = hcat[n,192](bf16) @ Wlin[192,40] + blin.
// 64-row tile per 256-thread block; thread = 2 rows x 5 cols; Wt in LDS at
// pitch 196; pool reused as epilogue staging for coalesced float4 stores.
// ---------------------------------------------------------------------------
__global__ __launch_bounds__(256) void final_gemm(const unsigned short* __restrict__ hcat,
                                                  const float* __restrict__ Wt,
                                                  const float* __restrict__ b,
                                                  float* __restrict__ out, int n) {
    __shared__ float pool[OUT_DIM * W_PITCH];  // 31360 B
    int tid = threadIdx.x;
    for (int i = tid; i < OUT_DIM * 48; i += 256) {
        int c = i / 48;
        int q = (i - c * 48) * 4;
        *(float4*)(pool + c * W_PITCH + q) = *(const float4*)(Wt + (long)c * JK_DIM + q);
    }
    __syncthreads();

    int rg = tid >> 3;
    int cg = tid & 7;
    int c0 = cg * 5;
    int row0 = blockIdx.x * 64;
    int r0 = row0 + rg * 2;
    int ra = r0 < n ? r0 : n - 1;
    int rb = r0 + 1 < n ? r0 + 1 : n - 1;
    const unsigned short* ha = hcat + (long)ra * JK_DIM;
    const unsigned short* hb = hcat + (long)rb * JK_DIM;

    float acc[2][5];
#pragma unroll
    for (int r = 0; r < 2; ++r)
#pragma unroll
        for (int i = 0; i < 5; ++i) acc[r][i] = 0.f;

#pragma unroll 4
    for (int k = 0; k < JK_DIM; k += 4) {
        uint2 ua = *(const uint2*)(ha + k);
        uint2 ub = *(const uint2*)(hb + k);
        float4 va = make_float4(blo(ua.x), bhi(ua.x), blo(ua.y), bhi(ua.y));
        float4 vb = make_float4(blo(ub.x), bhi(ub.x), blo(ub.y), bhi(ub.y));
        float4 w0 = *(const float4*)(pool + (c0 + 0) * W_PITCH + k);
        float4 w1 = *(const float4*)(pool + (c0 + 1) * W_PITCH + k);
        float4 w2 = *(const float4*)(pool + (c0 + 2) * W_PITCH + k);
        float4 w3 = *(const float4*)(pool + (c0 + 3) * W_PITCH + k);
        float4 w4 = *(const float4*)(pool + (c0 + 4) * W_PITCH + k);
        acc[0][0] += va.x * w0.x + va.y * w0.y + va.z * w0.z + va.w * w0.w;
        acc[0][1] += va.x * w1.x + va.y * w1.y + va.z * w1.z + va.w * w1.w;
        acc[0][2] += va.x * w2.x + va.y * w2.y + va.z * w2.z + va.w * w2.w;
        acc[0][3] += va.x * w3.x + va.y * w3.y + va.z * w3.z + va.w * w3.w;
        acc[0][4] += va.x * w4.x + va.y * w4.y + va.z * w4.z + va.w * w4.w;
        acc[1][0] += vb.x * w0.x + vb.y * w0.y + vb.z * w0.z + vb.w * w0.w;
        acc[1][1] += vb.x * w1.x + vb.y * w1.y + vb.z * w1.z + vb.w * w1.w;
        acc[1][2] += vb.x * w2.x + vb.y * w2.y + vb.z * w2.z + vb.w * w2.w;
        acc[1][3] += vb.x * w3.x + vb.y * w3.y + vb.z * w3.z + vb.w * w3.w;
        acc[1][4] += vb.x * w4.x + vb.y * w4.y + vb.z * w4.z + vb.w * w4.w;
    }

    __syncthreads();
#pragma unroll
    for (int r = 0; r < 2; ++r)
#pragma unroll
        for (int i = 0; i < 5; ++i)
            pool[(rg * 2 + r) * FG_PITCH + c0 + i] = acc[r][i] + b[c0 + i];
    __syncthreads();

    if (row0 + 64 <= n) {
        for (int i = tid; i < 64 * OUT_DIM / 4; i += 256) {
            int f = i * 4;
            int row = f / OUT_DIM;
            int col = f - row * OUT_DIM;
            *(float4*)(out + (long)(row0 + row) * OUT_DIM + col) =
                *(const float4*)(pool + row * FG_PITCH + col);
        }
    } else {
        for (int i = tid; i < 64 * OUT_DIM; i += 256) {
            int row = i / OUT_DIM;
            int col = i - row * OUT_DIM;
            if (row0 + row < n)
                out[(long)(row0 + row) * OUT_DIM + col] = pool[row * FG_PITCH + col];
        }
    }
}

// ---------------------------------------------------------------------------
extern "C" void kernel_launch(void* const* d_in, const int* in_sizes, int n_in,
                              void* d_out, int out_size, void* d_ws, size_t ws_size,
                              hipStream_t stream) {
    const float* x    = (const float*)d_in[0];
    const int*   ei   = (const int*)d_in[1];
    const float* ew   = (const float*)d_in[2];
    const float* W1   = (const float*)d_in[3];
    const float* b1   = (const float*)d_in[4];
    const float* W2   = (const float*)d_in[5];
    const float* b2   = (const float*)d_in[6];
    const float* W3   = (const float*)d_in[7];
    const float* b3   = (const float*)d_in[8];
    const float* Wlin = (const float*)d_in[9];
    const float* blin = (const float*)d_in[10];
    float* out = (float*)d_out;

    const int N = in_sizes[0] / 128;   // 50000
    const int E = in_sizes[2];         // 800000
    const int* src = ei;
    const int* dst = ei + E;
    const int PART = (N + 7) / 8;      // 6250 nodes per XCD partition

    // Workspace: linb(bf16) | hcatb(bf16) | deg,off,pos [N] | bsum | Wt | ecsr
    char* wsb = (char*)d_ws;
    unsigned short* linb  = (unsigned short*)wsb;   wsb += (long)N * HID * 2;
    unsigned short* hcatb = (unsigned short*)wsb;   wsb += (long)N * JK_DIM * 2;
    int* deg    = (int*)wsb;                        wsb += (long)N * 4;
    int* off    = (int*)wsb;                        wsb += (long)N * 4;
    int* pos    = (int*)wsb;                        wsb += (long)N * 4;
    int* bsum   = (int*)wsb;                        wsb += 256 * 4;
    float* Wt   = (float*)wsb;                      wsb += (long)JK_DIM * OUT_DIM * 4;
    unsigned* ecsr = (unsigned*)wsb;

    dim3 blk(256);
    const int nblkN = (N + 255) / 256;     // 196
    dim3 gN(nblkN);
    dim3 gHist(8 * 104);                   // 8 partitions x 104 blocks
    dim3 gFG(2400);                        // fused fill(1600 = 8x200) + gemm1(800)
    dim3 gGemm((N + 63) / 64);
    dim3 gAgg((N + 31) / 32);              // 8 nodes per wave
    dim3 gFin((N + 63) / 64);

    unsigned short* h1 = hcatb;            // columns [0,64)   of hcat[N,192]
    unsigned short* h2 = hcatb + HID;      // columns [64,128)
    unsigned short* h3 = hcatb + 2 * HID;  // columns [128,192)

    // ---- prep (zero deg + transpose Wlin), hist, scans ----
    prep<<<gN, blk, 0, stream>>>(deg, N, Wlin, Wt);
    hist_dst<<<gHist, blk, 0, stream>>>(dst, deg, E, PART);
    scan_a<<<gN, blk, 0, stream>>>(deg, off, bsum, N);
    scan_b<<<1, blk, 0, stream>>>(bsum, nblkN);
    scan_c<<<gN, blk, 0, stream>>>(off, bsum, pos, N);

    // ---- fused CSR fill + layer-1 GEMM ----
    fill_and_gemm<<<gFG, blk, 0, stream>>>(src, dst, ew, pos, ecsr, E, PART,
                                           x, W1, linb, N);
    aggregate<<<gAgg, blk, 0, stream>>>(linb, ecsr, off, deg, b1, h1, N);

    // ---- layer 2 (K=64, bf16 input from hcat col block) ----
    gemm_b16in<<<gGemm, blk, 0, stream>>>(h1, W2, linb, N);
    aggregate<<<gAgg, blk, 0, stream>>>(linb, ecsr, off, deg, b2, h2, N);

    // ---- layer 3 ----
    gemm_b16in<<<gGemm, blk, 0, stream>>>(h2, W3, linb, N);
    aggregate<<<gAgg, blk, 0, stream>>>(linb, ecsr, off, deg, b3, h3, N);

    // ---- JK linear ----
    final_gemm<<<gFin, blk, 0, stream>>>(hcatb, Wt, blin, out, N);
}